// Round 1
// baseline (856.214 us; speedup 1.0000x reference)
//
#include <hip/hip_runtime.h>
#include <cmath>

#define B_  2
#define S_  2048
#define D_  1024
#define H_  16
#define HD_ 64
#define FF_ 4096
#define M_  4096  /* B_*S_ */

typedef __attribute__((ext_vector_type(8))) __bf16 bf16x8;
typedef __attribute__((ext_vector_type(4))) __bf16 bf16x4;
typedef __attribute__((ext_vector_type(4))) float  f32x4;

__device__ __forceinline__ void gload_lds16(void* lds, const void* g) {
    __builtin_amdgcn_global_load_lds(
        (const __attribute__((address_space(1))) unsigned int*)g,
        (__attribute__((address_space(3))) unsigned int*)lds,
        16, 0, 0);
}

// ---------------- transpose + cast fp32 [K][N] -> bf16 [N][K] ----------------
__global__ __launch_bounds__(256)
void tcast(const float* __restrict__ src, __bf16* __restrict__ dst, int K, int N)
{
    __shared__ float t[32][33];
    int tx = threadIdx.x & 31, ty = threadIdx.x >> 5;   // ty 0..7
    int k0 = blockIdx.y * 32, n0 = blockIdx.x * 32;
#pragma unroll
    for (int i = 0; i < 4; ++i)
        t[ty + i * 8][tx] = src[(size_t)(k0 + ty + i * 8) * N + n0 + tx];
    __syncthreads();
#pragma unroll
    for (int i = 0; i < 4; ++i)
        dst[(size_t)(n0 + ty + i * 8) * K + k0 + tx] = (__bf16)t[tx][ty + i * 8];
}

// ---------------- tiny fp32 GEMV: out[b][col] = inp[b]·W[:,col] + bias -------
__global__ __launch_bounds__(256)
void colgemv(const float* __restrict__ inp, const float* __restrict__ W,
             const float* __restrict__ bias, float* __restrict__ out, int K, int N)
{
    int b = blockIdx.y;
    int col = blockIdx.x * 256 + threadIdx.x;
    float acc = bias[col];
    const float* ip = inp + (size_t)b * K;
    for (int k = 0; k < K; ++k) acc += ip[k] * W[(size_t)k * N + col];
    out[(size_t)b * N + col] = acc;
}

// ---------------- LayerNorm row (D=1024) + cast bf16 ------------------------
__global__ __launch_bounds__(256)
void ln_cast(const float* __restrict__ x, const float* __restrict__ g,
             const float* __restrict__ be, __bf16* __restrict__ out)
{
    int row = blockIdx.x, tid = threadIdx.x;
    const float4* xp = (const float4*)(x + (size_t)row * D_);
    float4 v = xp[tid];
    float s  = v.x + v.y + v.z + v.w;
    float s2 = v.x * v.x + v.y * v.y + v.z * v.z + v.w * v.w;
#pragma unroll
    for (int off = 32; off > 0; off >>= 1) {
        s  += __shfl_down(s, off);
        s2 += __shfl_down(s2, off);
    }
    __shared__ float rs[4], rs2[4];
    int wid = tid >> 6, lane = tid & 63;
    if (lane == 0) { rs[wid] = s; rs2[wid] = s2; }
    __syncthreads();
    float tot  = rs[0] + rs[1] + rs[2] + rs[3];
    float tot2 = rs2[0] + rs2[1] + rs2[2] + rs2[3];
    float mean = tot * (1.0f / D_);
    float var  = tot2 * (1.0f / D_) - mean * mean;
    float rstd = rsqrtf(var + 1e-5f);
    float4 gv = ((const float4*)g)[tid];
    float4 bv = ((const float4*)be)[tid];
    bf16x4 ov;
    ov[0] = (__bf16)((v.x - mean) * rstd * gv.x + bv.x);
    ov[1] = (__bf16)((v.y - mean) * rstd * gv.y + bv.y);
    ov[2] = (__bf16)((v.z - mean) * rstd * gv.z + bv.z);
    ov[3] = (__bf16)((v.w - mean) * rstd * gv.w + bv.w);
    ((bf16x4*)(out + (size_t)row * D_))[tid] = ov;
}

// ---------------- RoPE (pairs d <-> d+512, pre-head-split) + cast + head layout
__global__ __launch_bounds__(128)
void rope_cast(const float* __restrict__ qf, const float* __restrict__ cosp,
               const float* __restrict__ sinp, __bf16* __restrict__ out, float scale)
{
    int row = blockIdx.x, tid = threadIdx.x;
    int b = row >> 11, s = row & 2047;
    float4 x1 = ((const float4*)(qf + (size_t)row * D_))[tid];
    float4 x2 = ((const float4*)(qf + (size_t)row * D_ + 512))[tid];
    float4 c  = ((const float4*)(cosp + (size_t)s * 512))[tid];
    float4 sn = ((const float4*)(sinp + (size_t)s * 512))[tid];
    int d0 = tid * 4;
    int h1 = d0 >> 6, dd = d0 & 63;
    bf16x4 o1, o2;
    o1[0] = (__bf16)((x1.x * c.x - x2.x * sn.x) * scale);
    o1[1] = (__bf16)((x1.y * c.y - x2.y * sn.y) * scale);
    o1[2] = (__bf16)((x1.z * c.z - x2.z * sn.z) * scale);
    o1[3] = (__bf16)((x1.w * c.w - x2.w * sn.w) * scale);
    o2[0] = (__bf16)((x1.x * sn.x + x2.x * c.x) * scale);
    o2[1] = (__bf16)((x1.y * sn.y + x2.y * c.y) * scale);
    o2[2] = (__bf16)((x1.z * sn.z + x2.z * c.z) * scale);
    o2[3] = (__bf16)((x1.w * sn.w + x2.w * c.w) * scale);
    *(bf16x4*)(out + ((size_t)((b * H_ + h1) * S_ + s) * HD_) + dd) = o1;
    *(bf16x4*)(out + ((size_t)((b * H_ + h1 + 8) * S_ + s) * HD_) + dd) = o2;
}

// ---------------- per-head transpose Vh[bh][s][d] -> Vt[bh][d][s] ------------
__global__ __launch_bounds__(256)
void vtrans(const __bf16* __restrict__ Vh, __bf16* __restrict__ Vt)
{
    __shared__ __bf16 t[32][33];
    int tx = threadIdx.x & 31, ty = threadIdx.x >> 5;
    int bh = blockIdx.z;
    int s0 = blockIdx.y * 32, d0 = blockIdx.x * 32;
    const __bf16* src = Vh + (size_t)bh * S_ * HD_;
    __bf16* dst = Vt + (size_t)bh * HD_ * S_;
#pragma unroll
    for (int i = 0; i < 4; ++i)
        t[ty + i * 8][tx] = src[(size_t)(s0 + ty + i * 8) * HD_ + d0 + tx];
    __syncthreads();
#pragma unroll
    for (int i = 0; i < 4; ++i)
        dst[(size_t)(d0 + ty + i * 8) * S_ + s0 + tx] = t[tx][ty + i * 8];
}

// ---------------- bf16 MFMA GEMM, 128x128 tile, BK=64, Bt = B^T [N][K] -------
// MODE 0: outF = acc + bias                         (fp32)
// MODE 1: outH (bf16, head layout [b,h][s][d])
// MODE 2: outF = resid + acc + bias + extra[b][col] (fp32)
// MODE 3: outH = gelu(acc + bias)                   (bf16)
// MODE 4: outF = resid + acc + bias                 (fp32)
template<int MODE>
__global__ __launch_bounds__(256)
void gemm_bt(const __bf16* __restrict__ A, const __bf16* __restrict__ Bt,
             const float* __restrict__ bias, const float* __restrict__ resid,
             const float* __restrict__ extra, float* __restrict__ outF,
             __bf16* __restrict__ outH, int M, int N, int K)
{
    __shared__ __align__(16) __bf16 As[128 * 64];
    __shared__ __align__(16) __bf16 Bs[128 * 64];
    const int tid = threadIdx.x;
    const int wid = tid >> 6, lane = tid & 63;
    const int m0 = blockIdx.y * 128, n0 = blockIdx.x * 128;
    const int wm = wid >> 1, wn = wid & 1;
    const int l15 = lane & 15, l16 = lane >> 4;

    f32x4 acc[4][4] = {};

    char* asb = (char*)As;
    char* bsb = (char*)Bs;
    const char* ag = (const char*)A;
    const char* bg = (const char*)Bt;
    const int srow = lane >> 3;                 // 0..7
    const int scolsw = ((lane & 7) * 16) ^ (srow << 4);

    for (int k0 = 0; k0 < K; k0 += 64) {
        __syncthreads();
#pragma unroll
        for (int i = 0; i < 4; ++i) {
            int j = wid * 4 + i;
            int row = j * 8 + srow;
            gload_lds16(asb + j * 1024,
                        ag + (size_t)(m0 + row) * (K * 2) + k0 * 2 + scolsw);
        }
#pragma unroll
        for (int i = 0; i < 4; ++i) {
            int j = wid * 4 + i;
            int row = j * 8 + srow;
            gload_lds16(bsb + j * 1024,
                        bg + (size_t)(n0 + row) * (K * 2) + k0 * 2 + scolsw);
        }
        __syncthreads();

        bf16x8 af[4][2], bfr[4][2];
#pragma unroll
        for (int mi = 0; mi < 4; ++mi) {
            int row = wm * 64 + mi * 16 + l15;
            int sw = (row & 7) << 4;
#pragma unroll
            for (int kk = 0; kk < 2; ++kk)
                af[mi][kk] = *(const bf16x8*)(asb + row * 128 + (((l16 * 16 + kk * 64)) ^ sw));
        }
#pragma unroll
        for (int ni = 0; ni < 4; ++ni) {
            int row = wn * 64 + ni * 16 + l15;
            int sw = (row & 7) << 4;
#pragma unroll
            for (int kk = 0; kk < 2; ++kk)
                bfr[ni][kk] = *(const bf16x8*)(bsb + row * 128 + (((l16 * 16 + kk * 64)) ^ sw));
        }
#pragma unroll
        for (int mi = 0; mi < 4; ++mi)
#pragma unroll
            for (int ni = 0; ni < 4; ++ni) {
                acc[mi][ni] = __builtin_amdgcn_mfma_f32_16x16x32_bf16(af[mi][0], bfr[ni][0], acc[mi][ni], 0, 0, 0);
                acc[mi][ni] = __builtin_amdgcn_mfma_f32_16x16x32_bf16(af[mi][1], bfr[ni][1], acc[mi][ni], 0, 0, 0);
            }
    }

#pragma unroll
    for (int mi = 0; mi < 4; ++mi)
#pragma unroll
        for (int ni = 0; ni < 4; ++ni) {
            int gc = n0 + wn * 64 + ni * 16 + l15;
            float bb = bias[gc];
#pragma unroll
            for (int r = 0; r < 4; ++r) {
                int gr = m0 + wm * 64 + mi * 16 + l16 * 4 + r;
                float v = acc[mi][ni][r] + bb;
                size_t idx = (size_t)gr * N + gc;
                if constexpr (MODE == 0) {
                    outF[idx] = v;
                } else if constexpr (MODE == 1) {
                    int b = gr >> 11, s = gr & 2047, hh = gc >> 6, dd = gc & 63;
                    outH[((size_t)(b * H_ + hh) * S_ + s) * HD_ + dd] = (__bf16)v;
                } else if constexpr (MODE == 2) {
                    int b = gr >> 11;
                    outF[idx] = resid[idx] + v + extra[(size_t)b * N + gc];
                } else if constexpr (MODE == 3) {
                    outH[idx] = (__bf16)(0.5f * v * (1.0f + erff(v * 0.70710678118f)));
                } else {
                    outF[idx] = resid[idx] + v;
                }
            }
        }
}

// ---------------- flash attention: Qh/Kh [bh][s][64], Vt [bh][64][s] ---------
__global__ __launch_bounds__(256)
void attn_fwd(const __bf16* __restrict__ Qh, const __bf16* __restrict__ Kh,
              const __bf16* __restrict__ Vt, __bf16* __restrict__ O)
{
    __shared__ __align__(16) char smem[24576];
    char* Kl = smem;
    char* Vl = smem + 8192;
    char* Pl = smem + 16384;
    const int tid = threadIdx.x, wid = tid >> 6, lane = tid & 63;
    const int l15 = lane & 15, l16 = lane >> 4;
    const int bh = blockIdx.y;
    const int q0 = blockIdx.x * 64 + wid * 16;
    const size_t qkbase = (size_t)bh * S_ * HD_;

    bf16x8 qf[2];
    {
        const __bf16* qp = Qh + qkbase + (size_t)(q0 + l15) * HD_ + l16 * 8;
        qf[0] = *(const bf16x8*)qp;
        qf[1] = *(const bf16x8*)(qp + 32);
    }
    float m = -1e30f, sum = 0.f;
    f32x4 o[4] = {};
    const int srow = lane >> 3;
    const int scolsw = ((lane & 7) * 16) ^ (srow << 4);
    const char* kg = (const char*)(Kh + qkbase);
    const char* vg = (const char*)(Vt + (size_t)bh * HD_ * S_);

    for (int kt = 0; kt < S_ / 64; ++kt) {
        int s0 = kt * 64;
        __syncthreads();
#pragma unroll
        for (int c = 0; c < 2; ++c) {
            int j = wid * 2 + c;
            int row = j * 8 + srow;
            gload_lds16(Kl + j * 1024, kg + (size_t)(s0 + row) * 128 + scolsw);
            gload_lds16(Vl + j * 1024, vg + (size_t)row * (S_ * 2) + s0 * 2 + scolsw);
        }
        __syncthreads();

        // S^T = K · Q^T : st[t] holds score(k = s0+t*16+l16*4+r, q = q0+l15)
        f32x4 st[4];
#pragma unroll
        for (int t = 0; t < 4; ++t) {
            int row = t * 16 + l15;
            int sw = (row & 7) << 4;
            bf16x8 ak0 = *(const bf16x8*)(Kl + row * 128 + ((l16 * 16) ^ sw));
            bf16x8 ak1 = *(const bf16x8*)(Kl + row * 128 + ((l16 * 16 + 64) ^ sw));
            f32x4 z = {0.f, 0.f, 0.f, 0.f};
            z = __builtin_amdgcn_mfma_f32_16x16x32_bf16(ak0, qf[0], z, 0, 0, 0);
            st[t] = __builtin_amdgcn_mfma_f32_16x16x32_bf16(ak1, qf[1], z, 0, 0, 0);
        }
        // online softmax for q-row l15 (replicated over the 4 lane groups)
        float rmax = -1e30f;
#pragma unroll
        for (int t = 0; t < 4; ++t)
#pragma unroll
            for (int r = 0; r < 4; ++r) rmax = fmaxf(rmax, st[t][r]);
        rmax = fmaxf(rmax, __shfl_xor(rmax, 16));
        rmax = fmaxf(rmax, __shfl_xor(rmax, 32));
        float mnew = fmaxf(m, rmax);
        float corr = __expf(m - mnew);
        float rsum = 0.f;
        float p[4][4];
#pragma unroll
        for (int t = 0; t < 4; ++t)
#pragma unroll
            for (int r = 0; r < 4; ++r) { p[t][r] = __expf(st[t][r] - mnew); rsum += p[t][r]; }
        rsum += __shfl_xor(rsum, 16);
        rsum += __shfl_xor(rsum, 32);
        sum = sum * corr + rsum;
        m = mnew;
        // P -> wave-private LDS as P[q=l15][k], swizzled
        {
            char* pw = Pl + wid * 2048 + l15 * 128;
            int sw = (l15 & 7) << 4;
#pragma unroll
            for (int t = 0; t < 4; ++t) {
                bf16x4 pk;
                pk[0] = (__bf16)p[t][0]; pk[1] = (__bf16)p[t][1];
                pk[2] = (__bf16)p[t][2]; pk[3] = (__bf16)p[t][3];
                *(bf16x4*)(pw + ((t * 32 + l16 * 8) ^ sw)) = pk;
            }
        }
        // rescale O (output rows are q = l16*4+r)
        float c0 = __shfl(corr, l16 * 4 + 0);
        float c1 = __shfl(corr, l16 * 4 + 1);
        float c2 = __shfl(corr, l16 * 4 + 2);
        float c3 = __shfl(corr, l16 * 4 + 3);
#pragma unroll
        for (int dg = 0; dg < 4; ++dg) {
            o[dg][0] *= c0; o[dg][1] *= c1; o[dg][2] *= c2; o[dg][3] *= c3;
        }
        // PV: O[q][d] += P[q][k] · V[k][d]
        {
            const char* pr = Pl + wid * 2048 + l15 * 128;
            int swp = (l15 & 7) << 4;
            bf16x8 ap0 = *(const bf16x8*)(pr + ((l16 * 16) ^ swp));
            bf16x8 ap1 = *(const bf16x8*)(pr + ((l16 * 16 + 64) ^ swp));
#pragma unroll
            for (int dg = 0; dg < 4; ++dg) {
                int row = dg * 16 + l15;
                int sw = (row & 7) << 4;
                bf16x8 bv0 = *(const bf16x8*)(Vl + row * 128 + ((l16 * 16) ^ sw));
                bf16x8 bv1 = *(const bf16x8*)(Vl + row * 128 + ((l16 * 16 + 64) ^ sw));
                o[dg] = __builtin_amdgcn_mfma_f32_16x16x32_bf16(ap0, bv0, o[dg], 0, 0, 0);
                o[dg] = __builtin_amdgcn_mfma_f32_16x16x32_bf16(ap1, bv1, o[dg], 0, 0, 0);
            }
        }
    }
    int b = bh >> 4, hh = bh & 15;
#pragma unroll
    for (int r = 0; r < 4; ++r) {
        float inv = 1.0f / __shfl(sum, l16 * 4 + r);
        int qg = q0 + l16 * 4 + r;
        __bf16* op = O + ((size_t)(b * S_ + qg) * D_) + hh * HD_;
#pragma unroll
        for (int dg = 0; dg < 4; ++dg)
            op[dg * 16 + l15] = (__bf16)(o[dg][r] * inv);
    }
}

// -----------------------------------------------------------------------------
extern "C" void kernel_launch(void* const* d_in, const int* in_sizes, int n_in,
                              void* d_out, int out_size, void* d_ws, size_t ws_size,
                              hipStream_t stream)
{
    (void)in_sizes; (void)n_in; (void)out_size; (void)ws_size;
    const float* x    = (const float*)d_in[0];
    const float* cond = (const float*)d_in[1];
    const float* cosp = (const float*)d_in[2];
    const float* sinp = (const float*)d_in[3];
    const float* Wq = (const float*)d_in[4];  const float* bq = (const float*)d_in[5];
    const float* Wk = (const float*)d_in[6];  const float* bk = (const float*)d_in[7];
    const float* Wv = (const float*)d_in[8];  const float* bv = (const float*)d_in[9];
    const float* Wo = (const float*)d_in[10]; const float* bo = (const float*)d_in[11];
    // d_in[12..15] = Wqc,bqc,Wkc,bkc : dead code (softmax over 1 key == 1)
    const float* Wvc = (const float*)d_in[16]; const float* bvc = (const float*)d_in[17];
    const float* Woc = (const float*)d_in[18]; const float* boc = (const float*)d_in[19];
    const float* W1 = (const float*)d_in[20]; const float* b1 = (const float*)d_in[21];
    const float* W2 = (const float*)d_in[22]; const float* b2 = (const float*)d_in[23];
    const float* g1 = (const float*)d_in[24]; const float* be1 = (const float*)d_in[25];
    // g2/be2 dead
    const float* g3 = (const float*)d_in[28]; const float* be3 = (const float*)d_in[29];

    char* ws = (char*)d_ws;
    const size_t MB = 1ull << 20;
    __bf16* WqT  = (__bf16*)(ws + 0 * MB);
    __bf16* WkT  = (__bf16*)(ws + 2 * MB);
    __bf16* WvT  = (__bf16*)(ws + 4 * MB);
    __bf16* WoT  = (__bf16*)(ws + 6 * MB);
    __bf16* W1T  = (__bf16*)(ws + 8 * MB);
    __bf16* W2T  = (__bf16*)(ws + 16 * MB);
    __bf16* xn   = (__bf16*)(ws + 24 * MB);
    __bf16* Qh   = (__bf16*)(ws + 32 * MB);
    __bf16* Kh   = (__bf16*)(ws + 40 * MB);
    __bf16* Vt   = (__bf16*)(ws + 48 * MB);
    __bf16* oflat= (__bf16*)(ws + 56 * MB);
    __bf16* hbuf = (__bf16*)(ws + 32 * MB);   // reuses Qh/Kh/Vt/oflat (dead by then)
    float*  x2   = (float*)(ws + 64 * MB);
    float*  qkf  = (float*)(ws + 80 * MB);    // fp32 pre-RoPE scratch
    __bf16* Vh   = (__bf16*)(ws + 80 * MB);   // reuses qkf (dead after RoPE-K)
    float*  vc   = (float*)(ws + 96 * MB);
    float*  ocp  = (float*)(ws + 96 * MB + 16384);

    // weights -> bf16 transposed
    tcast<<<dim3(32, 32),  256, 0, stream>>>(Wq, WqT, 1024, 1024);
    tcast<<<dim3(32, 32),  256, 0, stream>>>(Wk, WkT, 1024, 1024);
    tcast<<<dim3(32, 32),  256, 0, stream>>>(Wv, WvT, 1024, 1024);
    tcast<<<dim3(32, 32),  256, 0, stream>>>(Wo, WoT, 1024, 1024);
    tcast<<<dim3(128, 32), 256, 0, stream>>>(W1, W1T, 1024, 4096);
    tcast<<<dim3(32, 128), 256, 0, stream>>>(W2, W2T, 4096, 1024);
    // cond path (block 2 collapses to a per-batch bias)
    colgemv<<<dim3(4, 2), 256, 0, stream>>>(cond, Wvc, bvc, vc, 1024, 1024);
    colgemv<<<dim3(4, 2), 256, 0, stream>>>(vc, Woc, boc, ocp, 1024, 1024);
    // LN1
    ln_cast<<<M_, 256, 0, stream>>>(x, g1, be1, xn);
    // Q, K (RoPE folds 1/sqrt(64) into Q), V
    gemm_bt<0><<<dim3(8, 32), 256, 0, stream>>>(xn, WqT, bq, nullptr, nullptr, qkf, nullptr, M_, 1024, 1024);
    rope_cast<<<M_, 128, 0, stream>>>(qkf, cosp, sinp, Qh, 0.125f);
    gemm_bt<0><<<dim3(8, 32), 256, 0, stream>>>(xn, WkT, bk, nullptr, nullptr, qkf, nullptr, M_, 1024, 1024);
    rope_cast<<<M_, 128, 0, stream>>>(qkf, cosp, sinp, Kh, 1.0f);
    gemm_bt<1><<<dim3(8, 32), 256, 0, stream>>>(xn, WvT, bv, nullptr, nullptr, nullptr, Vh, M_, 1024, 1024);
    vtrans<<<dim3(2, 64, 32), 256, 0, stream>>>(Vh, Vt);
    // attention
    attn_fwd<<<dim3(32, 32), 256, 0, stream>>>(Qh, Kh, Vt, oflat);
    // O-projection + residual + cond broadcast
    gemm_bt<2><<<dim3(8, 32), 256, 0, stream>>>(oflat, WoT, bo, x, ocp, x2, nullptr, M_, 1024, 1024);
    // LN3 + FFN
    ln_cast<<<M_, 256, 0, stream>>>(x2, g3, be3, xn);
    gemm_bt<3><<<dim3(32, 32), 256, 0, stream>>>(xn, W1T, b1, nullptr, nullptr, nullptr, hbuf, M_, 4096, 1024);
    gemm_bt<4><<<dim3(8, 32), 256, 0, stream>>>(hbuf, W2T, b2, x2, nullptr, (float*)d_out, nullptr, M_, 1024, 4096);
}

// Round 2
// 381.160 us; speedup vs baseline: 2.2463x; 2.2463x over previous
//
#include <hip/hip_runtime.h>
#include <cmath>

#define B_  2
#define S_  2048
#define D_  1024
#define H_  16
#define HD_ 64
#define FF_ 4096
#define M_  4096  /* B_*S_ */

typedef __attribute__((ext_vector_type(8))) __bf16 bf16x8;
typedef __attribute__((ext_vector_type(4))) __bf16 bf16x4;
typedef __attribute__((ext_vector_type(4))) float  f32x4;

__device__ __forceinline__ void gload_lds16(void* lds, const void* g) {
    __builtin_amdgcn_global_load_lds(
        (const __attribute__((address_space(1))) unsigned int*)g,
        (__attribute__((address_space(3))) unsigned int*)lds,
        16, 0, 0);
}

// ---------------- transpose + cast fp32 [K][N] -> bf16 [N][K] ----------------
__global__ __launch_bounds__(256)
void tcast(const float* __restrict__ src, __bf16* __restrict__ dst, int K, int N)
{
    __shared__ float t[32][33];
    int tx = threadIdx.x & 31, ty = threadIdx.x >> 5;   // ty 0..7
    int k0 = blockIdx.y * 32, n0 = blockIdx.x * 32;
#pragma unroll
    for (int i = 0; i < 4; ++i)
        t[ty + i * 8][tx] = src[(size_t)(k0 + ty + i * 8) * N + n0 + tx];
    __syncthreads();
#pragma unroll
    for (int i = 0; i < 4; ++i)
        dst[(size_t)(n0 + ty + i * 8) * K + k0 + tx] = (__bf16)t[tx][ty + i * 8];
}

// ---- latency-optimized fp32 GEMV: out[b][col] = inp[b]·W[:,col] + bias ------
// block = 256 thr = 4 waves; 16 cols/block, 16-way K-split, 8x unrolled loads.
__global__ __launch_bounds__(256)
void colgemv(const float* __restrict__ inp, const float* __restrict__ W,
             const float* __restrict__ bias, float* __restrict__ out, int K, int N)
{
    __shared__ float part[4][16];
    const int b = blockIdx.y;
    const int t = threadIdx.x;
    const int w = t >> 6, lane = t & 63;
    const int colIdx = lane & 15;
    const int col = blockIdx.x * 16 + colIdx;
    const int ks = w * 4 + (lane >> 4);      // 0..15
    const int kpt = K >> 4;                  // 64
    const float* ip = inp + (size_t)b * K + ks * kpt;
    const float* wp = W + (size_t)ks * kpt * N + col;
    float acc = 0.f;
#pragma unroll 8
    for (int i = 0; i < kpt; ++i)
        acc += ip[i] * wp[(size_t)i * N];
    acc += __shfl_xor(acc, 16);
    acc += __shfl_xor(acc, 32);
    if (lane < 16) part[w][colIdx] = acc;
    __syncthreads();
    if (t < 16) {
        float r = part[0][t] + part[1][t] + part[2][t] + part[3][t]
                + bias[blockIdx.x * 16 + t];
        out[(size_t)b * N + blockIdx.x * 16 + t] = r;
    }
}

// ---------------- LayerNorm row (D=1024) + cast bf16 ------------------------
__global__ __launch_bounds__(256)
void ln_cast(const float* __restrict__ x, const float* __restrict__ g,
             const float* __restrict__ be, __bf16* __restrict__ out)
{
    int row = blockIdx.x, tid = threadIdx.x;
    const float4* xp = (const float4*)(x + (size_t)row * D_);
    float4 v = xp[tid];
    float s  = v.x + v.y + v.z + v.w;
    float s2 = v.x * v.x + v.y * v.y + v.z * v.z + v.w * v.w;
#pragma unroll
    for (int off = 32; off > 0; off >>= 1) {
        s  += __shfl_down(s, off);
        s2 += __shfl_down(s2, off);
    }
    __shared__ float rs[4], rs2[4];
    int wid = tid >> 6, lane = tid & 63;
    if (lane == 0) { rs[wid] = s; rs2[wid] = s2; }
    __syncthreads();
    float tot  = rs[0] + rs[1] + rs[2] + rs[3];
    float tot2 = rs2[0] + rs2[1] + rs2[2] + rs2[3];
    float mean = tot * (1.0f / D_);
    float var  = tot2 * (1.0f / D_) - mean * mean;
    float rstd = rsqrtf(var + 1e-5f);
    float4 gv = ((const float4*)g)[tid];
    float4 bv = ((const float4*)be)[tid];
    bf16x4 ov;
    ov[0] = (__bf16)((v.x - mean) * rstd * gv.x + bv.x);
    ov[1] = (__bf16)((v.y - mean) * rstd * gv.y + bv.y);
    ov[2] = (__bf16)((v.z - mean) * rstd * gv.z + bv.z);
    ov[3] = (__bf16)((v.w - mean) * rstd * gv.w + bv.w);
    ((bf16x4*)(out + (size_t)row * D_))[tid] = ov;
}

// ---------------- RoPE (pairs d <-> d+512, pre-head-split) + cast + head layout
__global__ __launch_bounds__(128)
void rope_cast(const float* __restrict__ qf, const float* __restrict__ cosp,
               const float* __restrict__ sinp, __bf16* __restrict__ out, float scale)
{
    int row = blockIdx.x, tid = threadIdx.x;
    int b = row >> 11, s = row & 2047;
    float4 x1 = ((const float4*)(qf + (size_t)row * D_))[tid];
    float4 x2 = ((const float4*)(qf + (size_t)row * D_ + 512))[tid];
    float4 c  = ((const float4*)(cosp + (size_t)s * 512))[tid];
    float4 sn = ((const float4*)(sinp + (size_t)s * 512))[tid];
    int d0 = tid * 4;
    int h1 = d0 >> 6, dd = d0 & 63;
    bf16x4 o1, o2;
    o1[0] = (__bf16)((x1.x * c.x - x2.x * sn.x) * scale);
    o1[1] = (__bf16)((x1.y * c.y - x2.y * sn.y) * scale);
    o1[2] = (__bf16)((x1.z * c.z - x2.z * sn.z) * scale);
    o1[3] = (__bf16)((x1.w * c.w - x2.w * sn.w) * scale);
    o2[0] = (__bf16)((x1.x * sn.x + x2.x * c.x) * scale);
    o2[1] = (__bf16)((x1.y * sn.y + x2.y * c.y) * scale);
    o2[2] = (__bf16)((x1.z * sn.z + x2.z * c.z) * scale);
    o2[3] = (__bf16)((x1.w * sn.w + x2.w * c.w) * scale);
    *(bf16x4*)(out + ((size_t)((b * H_ + h1) * S_ + s) * HD_) + dd) = o1;
    *(bf16x4*)(out + ((size_t)((b * H_ + h1 + 8) * S_ + s) * HD_) + dd) = o2;
}

// ---------------- per-head transpose Vh[bh][s][d] -> Vt[bh][d][s] ------------
__global__ __launch_bounds__(256)
void vtrans(const __bf16* __restrict__ Vh, __bf16* __restrict__ Vt)
{
    __shared__ __bf16 t[32][33];
    int tx = threadIdx.x & 31, ty = threadIdx.x >> 5;
    int bh = blockIdx.z;
    int s0 = blockIdx.y * 32, d0 = blockIdx.x * 32;
    const __bf16* src = Vh + (size_t)bh * S_ * HD_;
    __bf16* dst = Vt + (size_t)bh * HD_ * S_;
#pragma unroll
    for (int i = 0; i < 4; ++i)
        t[ty + i * 8][tx] = src[(size_t)(s0 + ty + i * 8) * HD_ + d0 + tx];
    __syncthreads();
#pragma unroll
    for (int i = 0; i < 4; ++i)
        dst[(size_t)(d0 + ty + i * 8) * S_ + s0 + tx] = t[tx][ty + i * 8];
}

// ---------------- bf16 MFMA GEMM, 128x128 tile, BK=64, Bt = B^T [N][K] -------
// MODE 0: outF = acc + bias                         (fp32)
// MODE 1: outH (bf16, head layout [b,h][s][d])
// MODE 2: outF = resid + acc + bias + extra[b][col] (fp32)
// MODE 3: outH = gelu(acc + bias)                   (bf16)
// MODE 4: outF = resid + acc + bias                 (fp32)
template<int MODE>
__global__ __launch_bounds__(256)
void gemm_bt(const __bf16* __restrict__ A, const __bf16* __restrict__ Bt,
             const float* __restrict__ bias, const float* __restrict__ resid,
             const float* __restrict__ extra, float* __restrict__ outF,
             __bf16* __restrict__ outH, int M, int N, int K)
{
    __shared__ __align__(16) __bf16 As[128 * 64];
    __shared__ __align__(16) __bf16 Bs[128 * 64];
    const int tid = threadIdx.x;
    const int wid = tid >> 6, lane = tid & 63;
    const int m0 = blockIdx.y * 128, n0 = blockIdx.x * 128;
    const int wm = wid >> 1, wn = wid & 1;
    const int l15 = lane & 15, l16 = lane >> 4;

    f32x4 acc[4][4] = {};

    char* asb = (char*)As;
    char* bsb = (char*)Bs;
    const char* ag = (const char*)A;
    const char* bg = (const char*)Bt;
    const int srow = lane >> 3;                 // 0..7
    const int scolsw = ((lane & 7) * 16) ^ (srow << 4);

    for (int k0 = 0; k0 < K; k0 += 64) {
        __syncthreads();
#pragma unroll
        for (int i = 0; i < 4; ++i) {
            int j = wid * 4 + i;
            int row = j * 8 + srow;
            gload_lds16(asb + j * 1024,
                        ag + (size_t)(m0 + row) * (K * 2) + k0 * 2 + scolsw);
        }
#pragma unroll
        for (int i = 0; i < 4; ++i) {
            int j = wid * 4 + i;
            int row = j * 8 + srow;
            gload_lds16(bsb + j * 1024,
                        bg + (size_t)(n0 + row) * (K * 2) + k0 * 2 + scolsw);
        }
        __syncthreads();

        bf16x8 af[4][2], bfr[4][2];
#pragma unroll
        for (int mi = 0; mi < 4; ++mi) {
            int row = wm * 64 + mi * 16 + l15;
            int sw = (row & 7) << 4;
#pragma unroll
            for (int kk = 0; kk < 2; ++kk)
                af[mi][kk] = *(const bf16x8*)(asb + row * 128 + (((l16 * 16 + kk * 64)) ^ sw));
        }
#pragma unroll
        for (int ni = 0; ni < 4; ++ni) {
            int row = wn * 64 + ni * 16 + l15;
            int sw = (row & 7) << 4;
#pragma unroll
            for (int kk = 0; kk < 2; ++kk)
                bfr[ni][kk] = *(const bf16x8*)(bsb + row * 128 + (((l16 * 16 + kk * 64)) ^ sw));
        }
#pragma unroll
        for (int mi = 0; mi < 4; ++mi)
#pragma unroll
            for (int ni = 0; ni < 4; ++ni) {
                acc[mi][ni] = __builtin_amdgcn_mfma_f32_16x16x32_bf16(af[mi][0], bfr[ni][0], acc[mi][ni], 0, 0, 0);
                acc[mi][ni] = __builtin_amdgcn_mfma_f32_16x16x32_bf16(af[mi][1], bfr[ni][1], acc[mi][ni], 0, 0, 0);
            }
    }

#pragma unroll
    for (int mi = 0; mi < 4; ++mi)
#pragma unroll
        for (int ni = 0; ni < 4; ++ni) {
            int gc = n0 + wn * 64 + ni * 16 + l15;
            float bb = bias[gc];
#pragma unroll
            for (int r = 0; r < 4; ++r) {
                int gr = m0 + wm * 64 + mi * 16 + l16 * 4 + r;
                float v = acc[mi][ni][r] + bb;
                size_t idx = (size_t)gr * N + gc;
                if constexpr (MODE == 0) {
                    outF[idx] = v;
                } else if constexpr (MODE == 1) {
                    int b = gr >> 11, s = gr & 2047, hh = gc >> 6, dd = gc & 63;
                    outH[((size_t)(b * H_ + hh) * S_ + s) * HD_ + dd] = (__bf16)v;
                } else if constexpr (MODE == 2) {
                    int b = gr >> 11;
                    outF[idx] = resid[idx] + v + extra[(size_t)b * N + gc];
                } else if constexpr (MODE == 3) {
                    outH[idx] = (__bf16)(0.5f * v * (1.0f + erff(v * 0.70710678118f)));
                } else {
                    outF[idx] = resid[idx] + v;
                }
            }
        }
}

// ---------------- flash attention: Qh/Kh [bh][s][64], Vt [bh][64][s] ---------
__global__ __launch_bounds__(256)
void attn_fwd(const __bf16* __restrict__ Qh, const __bf16* __restrict__ Kh,
              const __bf16* __restrict__ Vt, __bf16* __restrict__ O)
{
    __shared__ __align__(16) char smem[24576];
    char* Kl = smem;
    char* Vl = smem + 8192;
    char* Pl = smem + 16384;
    const int tid = threadIdx.x, wid = tid >> 6, lane = tid & 63;
    const int l15 = lane & 15, l16 = lane >> 4;
    const int bh = blockIdx.y;
    const int q0 = blockIdx.x * 64 + wid * 16;
    const size_t qkbase = (size_t)bh * S_ * HD_;

    bf16x8 qf[2];
    {
        const __bf16* qp = Qh + qkbase + (size_t)(q0 + l15) * HD_ + l16 * 8;
        qf[0] = *(const bf16x8*)qp;
        qf[1] = *(const bf16x8*)(qp + 32);
    }
    float m = -1e30f, sum = 0.f;
    f32x4 o[4] = {};
    const int srow = lane >> 3;
    const int scolsw = ((lane & 7) * 16) ^ (srow << 4);
    const char* kg = (const char*)(Kh + qkbase);
    const char* vg = (const char*)(Vt + (size_t)bh * HD_ * S_);

    for (int kt = 0; kt < S_ / 64; ++kt) {
        int s0 = kt * 64;
        __syncthreads();
#pragma unroll
        for (int c = 0; c < 2; ++c) {
            int j = wid * 2 + c;
            int row = j * 8 + srow;
            gload_lds16(Kl + j * 1024, kg + (size_t)(s0 + row) * 128 + scolsw);
            gload_lds16(Vl + j * 1024, vg + (size_t)row * (S_ * 2) + s0 * 2 + scolsw);
        }
        __syncthreads();

        // S^T = K · Q^T : st[t] holds score(k = s0+t*16+l16*4+r, q = q0+l15)
        f32x4 st[4];
#pragma unroll
        for (int t = 0; t < 4; ++t) {
            int row = t * 16 + l15;
            int sw = (row & 7) << 4;
            bf16x8 ak0 = *(const bf16x8*)(Kl + row * 128 + ((l16 * 16) ^ sw));
            bf16x8 ak1 = *(const bf16x8*)(Kl + row * 128 + ((l16 * 16 + 64) ^ sw));
            f32x4 z = {0.f, 0.f, 0.f, 0.f};
            z = __builtin_amdgcn_mfma_f32_16x16x32_bf16(ak0, qf[0], z, 0, 0, 0);
            st[t] = __builtin_amdgcn_mfma_f32_16x16x32_bf16(ak1, qf[1], z, 0, 0, 0);
        }
        // online softmax for q-row l15 (replicated over the 4 lane groups)
        float rmax = -1e30f;
#pragma unroll
        for (int t = 0; t < 4; ++t)
#pragma unroll
            for (int r = 0; r < 4; ++r) rmax = fmaxf(rmax, st[t][r]);
        rmax = fmaxf(rmax, __shfl_xor(rmax, 16));
        rmax = fmaxf(rmax, __shfl_xor(rmax, 32));
        float mnew = fmaxf(m, rmax);
        float corr = __expf(m - mnew);
        float rsum = 0.f;
        float p[4][4];
#pragma unroll
        for (int t = 0; t < 4; ++t)
#pragma unroll
            for (int r = 0; r < 4; ++r) { p[t][r] = __expf(st[t][r] - mnew); rsum += p[t][r]; }
        rsum += __shfl_xor(rsum, 16);
        rsum += __shfl_xor(rsum, 32);
        sum = sum * corr + rsum;
        m = mnew;
        // P -> wave-private LDS as P[q=l15][k], swizzled
        {
            char* pw = Pl + wid * 2048 + l15 * 128;
            int sw = (l15 & 7) << 4;
#pragma unroll
            for (int t = 0; t < 4; ++t) {
                bf16x4 pk;
                pk[0] = (__bf16)p[t][0]; pk[1] = (__bf16)p[t][1];
                pk[2] = (__bf16)p[t][2]; pk[3] = (__bf16)p[t][3];
                *(bf16x4*)(pw + ((t * 32 + l16 * 8) ^ sw)) = pk;
            }
        }
        // rescale O (output rows are q = l16*4+r)
        float c0 = __shfl(corr, l16 * 4 + 0);
        float c1 = __shfl(corr, l16 * 4 + 1);
        float c2 = __shfl(corr, l16 * 4 + 2);
        float c3 = __shfl(corr, l16 * 4 + 3);
#pragma unroll
        for (int dg = 0; dg < 4; ++dg) {
            o[dg][0] *= c0; o[dg][1] *= c1; o[dg][2] *= c2; o[dg][3] *= c3;
        }
        // PV: O[q][d] += P[q][k] · V[k][d]
        {
            const char* pr = Pl + wid * 2048 + l15 * 128;
            int swp = (l15 & 7) << 4;
            bf16x8 ap0 = *(const bf16x8*)(pr + ((l16 * 16) ^ swp));
            bf16x8 ap1 = *(const bf16x8*)(pr + ((l16 * 16 + 64) ^ swp));
#pragma unroll
            for (int dg = 0; dg < 4; ++dg) {
                int row = dg * 16 + l15;
                int sw = (row & 7) << 4;
                bf16x8 bv0 = *(const bf16x8*)(Vl + row * 128 + ((l16 * 16) ^ sw));
                bf16x8 bv1 = *(const bf16x8*)(Vl + row * 128 + ((l16 * 16 + 64) ^ sw));
                o[dg] = __builtin_amdgcn_mfma_f32_16x16x32_bf16(ap0, bv0, o[dg], 0, 0, 0);
                o[dg] = __builtin_amdgcn_mfma_f32_16x16x32_bf16(ap1, bv1, o[dg], 0, 0, 0);
            }
        }
    }
    int b = bh >> 4, hh = bh & 15;
#pragma unroll
    for (int r = 0; r < 4; ++r) {
        float inv = 1.0f / __shfl(sum, l16 * 4 + r);
        int qg = q0 + l16 * 4 + r;
        __bf16* op = O + ((size_t)(b * S_ + qg) * D_) + hh * HD_;
#pragma unroll
        for (int dg = 0; dg < 4; ++dg)
            op[dg * 16 + l15] = (__bf16)(o[dg][r] * inv);
    }
}

// -----------------------------------------------------------------------------
extern "C" void kernel_launch(void* const* d_in, const int* in_sizes, int n_in,
                              void* d_out, int out_size, void* d_ws, size_t ws_size,
                              hipStream_t stream)
{
    (void)in_sizes; (void)n_in; (void)out_size; (void)ws_size;
    const float* x    = (const float*)d_in[0];
    const float* cond = (const float*)d_in[1];
    const float* cosp = (const float*)d_in[2];
    const float* sinp = (const float*)d_in[3];
    const float* Wq = (const float*)d_in[4];  const float* bq = (const float*)d_in[5];
    const float* Wk = (const float*)d_in[6];  const float* bk = (const float*)d_in[7];
    const float* Wv = (const float*)d_in[8];  const float* bv = (const float*)d_in[9];
    const float* Wo = (const float*)d_in[10]; const float* bo = (const float*)d_in[11];
    // d_in[12..15] = Wqc,bqc,Wkc,bkc : dead code (softmax over 1 key == 1)
    const float* Wvc = (const float*)d_in[16]; const float* bvc = (const float*)d_in[17];
    const float* Woc = (const float*)d_in[18]; const float* boc = (const float*)d_in[19];
    const float* W1 = (const float*)d_in[20]; const float* b1 = (const float*)d_in[21];
    const float* W2 = (const float*)d_in[22]; const float* b2 = (const float*)d_in[23];
    const float* g1 = (const float*)d_in[24]; const float* be1 = (const float*)d_in[25];
    // g2/be2 dead
    const float* g3 = (const float*)d_in[28]; const float* be3 = (const float*)d_in[29];

    char* ws = (char*)d_ws;
    const size_t MB = 1ull << 20;
    __bf16* WqT  = (__bf16*)(ws + 0 * MB);
    __bf16* WkT  = (__bf16*)(ws + 2 * MB);
    __bf16* WvT  = (__bf16*)(ws + 4 * MB);
    __bf16* WoT  = (__bf16*)(ws + 6 * MB);
    __bf16* W1T  = (__bf16*)(ws + 8 * MB);
    __bf16* W2T  = (__bf16*)(ws + 16 * MB);
    __bf16* xn   = (__bf16*)(ws + 24 * MB);
    __bf16* Qh   = (__bf16*)(ws + 32 * MB);
    __bf16* Kh   = (__bf16*)(ws + 40 * MB);
    __bf16* Vt   = (__bf16*)(ws + 48 * MB);
    __bf16* oflat= (__bf16*)(ws + 56 * MB);
    __bf16* hbuf = (__bf16*)(ws + 32 * MB);   // reuses Qh/Kh/Vt/oflat (dead by then)
    float*  x2   = (float*)(ws + 64 * MB);
    float*  qkf  = (float*)(ws + 80 * MB);    // fp32 pre-RoPE scratch
    __bf16* Vh   = (__bf16*)(ws + 80 * MB);   // reuses qkf (dead after RoPE-K)
    float*  vc   = (float*)(ws + 96 * MB);
    float*  ocp  = (float*)(ws + 96 * MB + 16384);

    // weights -> bf16 transposed
    tcast<<<dim3(32, 32),  256, 0, stream>>>(Wq, WqT, 1024, 1024);
    tcast<<<dim3(32, 32),  256, 0, stream>>>(Wk, WkT, 1024, 1024);
    tcast<<<dim3(32, 32),  256, 0, stream>>>(Wv, WvT, 1024, 1024);
    tcast<<<dim3(32, 32),  256, 0, stream>>>(Wo, WoT, 1024, 1024);
    tcast<<<dim3(128, 32), 256, 0, stream>>>(W1, W1T, 1024, 4096);
    tcast<<<dim3(32, 128), 256, 0, stream>>>(W2, W2T, 4096, 1024);
    // cond path (block 2 collapses to a per-batch bias)
    colgemv<<<dim3(64, 2), 256, 0, stream>>>(cond, Wvc, bvc, vc, 1024, 1024);
    colgemv<<<dim3(64, 2), 256, 0, stream>>>(vc, Woc, boc, ocp, 1024, 1024);
    // LN1
    ln_cast<<<M_, 256, 0, stream>>>(x, g1, be1, xn);
    // Q, K (RoPE folds 1/sqrt(64) into Q), V
    gemm_bt<0><<<dim3(8, 32), 256, 0, stream>>>(xn, WqT, bq, nullptr, nullptr, qkf, nullptr, M_, 1024, 1024);
    rope_cast<<<M_, 128, 0, stream>>>(qkf, cosp, sinp, Qh, 0.125f);
    gemm_bt<0><<<dim3(8, 32), 256, 0, stream>>>(xn, WkT, bk, nullptr, nullptr, qkf, nullptr, M_, 1024, 1024);
    rope_cast<<<M_, 128, 0, stream>>>(qkf, cosp, sinp, Kh, 1.0f);
    gemm_bt<1><<<dim3(8, 32), 256, 0, stream>>>(xn, WvT, bv, nullptr, nullptr, nullptr, Vh, M_, 1024, 1024);
    vtrans<<<dim3(2, 64, 32), 256, 0, stream>>>(Vh, Vt);
    // attention
    attn_fwd<<<dim3(32, 32), 256, 0, stream>>>(Qh, Kh, Vt, oflat);
    // O-projection + residual + cond broadcast
    gemm_bt<2><<<dim3(8, 32), 256, 0, stream>>>(oflat, WoT, bo, x, ocp, x2, nullptr, M_, 1024, 1024);
    // LN3 + FFN
    ln_cast<<<M_, 256, 0, stream>>>(x2, g3, be3, xn);
    gemm_bt<3><<<dim3(32, 32), 256, 0, stream>>>(xn, W1T, b1, nullptr, nullptr, nullptr, hbuf, M_, 4096, 1024);
    gemm_bt<4><<<dim3(8, 32), 256, 0, stream>>>(hbuf, W2T, b2, x2, nullptr, (float*)d_out, nullptr, M_, 1024, 4096);
}

// Round 3
// 286.931 us; speedup vs baseline: 2.9840x; 1.3284x over previous
//
#include <hip/hip_runtime.h>
#include <cmath>

#define B_  2
#define S_  2048
#define D_  1024
#define H_  16
#define HD_ 64
#define FF_ 4096
#define M_  4096  /* B_*S_ */

typedef __attribute__((ext_vector_type(8))) __bf16 bf16x8;
typedef __attribute__((ext_vector_type(4))) __bf16 bf16x4;
typedef __attribute__((ext_vector_type(4))) float  f32x4;

__device__ __forceinline__ void gload_lds16(void* lds, const void* g) {
    __builtin_amdgcn_global_load_lds(
        (const __attribute__((address_space(1))) unsigned int*)g,
        (__attribute__((address_space(3))) unsigned int*)lds,
        16, 0, 0);
}

#define FENCE() asm volatile("" ::: "memory")

// ---------------- transpose + cast fp32 [K][N] -> bf16 [N][K] ----------------
__global__ __launch_bounds__(256)
void tcast(const float* __restrict__ src, __bf16* __restrict__ dst, int K, int N)
{
    __shared__ float t[32][33];
    int tx = threadIdx.x & 31, ty = threadIdx.x >> 5;
    int k0 = blockIdx.y * 32, n0 = blockIdx.x * 32;
#pragma unroll
    for (int i = 0; i < 4; ++i)
        t[ty + i * 8][tx] = src[(size_t)(k0 + ty + i * 8) * N + n0 + tx];
    __syncthreads();
#pragma unroll
    for (int i = 0; i < 4; ++i)
        dst[(size_t)(n0 + ty + i * 8) * K + k0 + tx] = (__bf16)t[tx][ty + i * 8];
}

// ---------------- concat 3 bias vectors --------------------------------------
__global__ __launch_bounds__(256)
void catb(const float* __restrict__ a, const float* __restrict__ b,
          const float* __restrict__ c, float* __restrict__ o)
{
    int i = blockIdx.x * 256 + threadIdx.x;
    o[i] = i < 1024 ? a[i] : (i < 2048 ? b[i - 1024] : c[i - 2048]);
}

// ---- latency-optimized fp32 GEMV: out[b][col] = inp[b]·W[:,col] + bias ------
__global__ __launch_bounds__(256)
void colgemv(const float* __restrict__ inp, const float* __restrict__ W,
             const float* __restrict__ bias, float* __restrict__ out, int K, int N)
{
    __shared__ float part[4][16];
    const int b = blockIdx.y;
    const int t = threadIdx.x;
    const int w = t >> 6, lane = t & 63;
    const int colIdx = lane & 15;
    const int col = blockIdx.x * 16 + colIdx;
    const int ks = w * 4 + (lane >> 4);
    const int kpt = K >> 4;
    const float* ip = inp + (size_t)b * K + ks * kpt;
    const float* wp = W + (size_t)ks * kpt * N + col;
    float acc = 0.f;
#pragma unroll 8
    for (int i = 0; i < kpt; ++i)
        acc += ip[i] * wp[(size_t)i * N];
    acc += __shfl_xor(acc, 16);
    acc += __shfl_xor(acc, 32);
    if (lane < 16) part[w][colIdx] = acc;
    __syncthreads();
    if (t < 16) {
        float r = part[0][t] + part[1][t] + part[2][t] + part[3][t]
                + bias[blockIdx.x * 16 + t];
        out[(size_t)b * N + blockIdx.x * 16 + t] = r;
    }
}

// ---------------- LayerNorm row (D=1024) + cast bf16 -------------------------
__global__ __launch_bounds__(256)
void ln_cast(const float* __restrict__ x, const float* __restrict__ g,
             const float* __restrict__ be, __bf16* __restrict__ out)
{
    int row = blockIdx.x, tid = threadIdx.x;
    const float4* xp = (const float4*)(x + (size_t)row * D_);
    float4 v = xp[tid];
    float s  = v.x + v.y + v.z + v.w;
    float s2 = v.x * v.x + v.y * v.y + v.z * v.z + v.w * v.w;
#pragma unroll
    for (int off = 32; off > 0; off >>= 1) {
        s  += __shfl_down(s, off);
        s2 += __shfl_down(s2, off);
    }
    __shared__ float rs[4], rs2[4];
    int wid = tid >> 6, lane = tid & 63;
    if (lane == 0) { rs[wid] = s; rs2[wid] = s2; }
    __syncthreads();
    float tot  = rs[0] + rs[1] + rs[2] + rs[3];
    float tot2 = rs2[0] + rs2[1] + rs2[2] + rs2[3];
    float mean = tot * (1.0f / D_);
    float var  = tot2 * (1.0f / D_) - mean * mean;
    float rstd = rsqrtf(var + 1e-5f);
    float4 gv = ((const float4*)g)[tid];
    float4 bv = ((const float4*)be)[tid];
    bf16x4 ov;
    ov[0] = (__bf16)((v.x - mean) * rstd * gv.x + bv.x);
    ov[1] = (__bf16)((v.y - mean) * rstd * gv.y + bv.y);
    ov[2] = (__bf16)((v.z - mean) * rstd * gv.z + bv.z);
    ov[3] = (__bf16)((v.w - mean) * rstd * gv.w + bv.w);
    ((bf16x4*)(out + (size_t)row * D_))[tid] = ov;
}

// ------- RoPE from fused qkv buffer (bf16 [row][3072] slice at `off`) --------
__global__ __launch_bounds__(128)
void rope2(const __bf16* __restrict__ qkv, const float* __restrict__ cosp,
           const float* __restrict__ sinp, __bf16* __restrict__ out,
           int off, float scale)
{
    int row = blockIdx.x, tid = threadIdx.x;
    int b = row >> 11, s = row & 2047;
    bf16x4 a  = *(const bf16x4*)(qkv + (size_t)row * 3072 + off + tid * 4);
    bf16x4 bb = *(const bf16x4*)(qkv + (size_t)row * 3072 + off + 512 + tid * 4);
    float4 c  = ((const float4*)(cosp + (size_t)s * 512))[tid];
    float4 sn = ((const float4*)(sinp + (size_t)s * 512))[tid];
    float x1a = (float)a[0],  x1b = (float)a[1],  x1c = (float)a[2],  x1d = (float)a[3];
    float x2a = (float)bb[0], x2b = (float)bb[1], x2c = (float)bb[2], x2d = (float)bb[3];
    int d0 = tid * 4;
    int h1 = d0 >> 6, dd = d0 & 63;
    bf16x4 o1, o2;
    o1[0] = (__bf16)((x1a * c.x - x2a * sn.x) * scale);
    o1[1] = (__bf16)((x1b * c.y - x2b * sn.y) * scale);
    o1[2] = (__bf16)((x1c * c.z - x2c * sn.z) * scale);
    o1[3] = (__bf16)((x1d * c.w - x2d * sn.w) * scale);
    o2[0] = (__bf16)((x1a * sn.x + x2a * c.x) * scale);
    o2[1] = (__bf16)((x1b * sn.y + x2b * c.y) * scale);
    o2[2] = (__bf16)((x1c * sn.z + x2c * c.z) * scale);
    o2[3] = (__bf16)((x1d * sn.w + x2d * c.w) * scale);
    *(bf16x4*)(out + ((size_t)((b * H_ + h1) * S_ + s) * HD_) + dd) = o1;
    *(bf16x4*)(out + ((size_t)((b * H_ + h1 + 8) * S_ + s) * HD_) + dd) = o2;
}

// ------ per-head transpose from qkv buffer: v-slice -> Vt[bh][d][s] ----------
__global__ __launch_bounds__(256)
void vtrans2(const __bf16* __restrict__ qkv, __bf16* __restrict__ Vt)
{
    __shared__ __bf16 t[32][33];
    int tx = threadIdx.x & 31, ty = threadIdx.x >> 5;
    int bh = blockIdx.z;
    int b = bh >> 4, h = bh & 15;
    int s0 = blockIdx.y * 32, d0 = blockIdx.x * 32;
    __bf16* dst = Vt + (size_t)bh * HD_ * S_;
#pragma unroll
    for (int i = 0; i < 4; ++i)
        t[ty + i * 8][tx] = qkv[(size_t)(b * 2048 + s0 + ty + i * 8) * 3072
                                + 2048 + h * 64 + d0 + tx];
    __syncthreads();
#pragma unroll
    for (int i = 0; i < 4; ++i)
        dst[(size_t)(d0 + ty + i * 8) * S_ + s0 + tx] = t[tx][ty + i * 8];
}

// =============================================================================
// gemm8: 256x256 tile, BK=64, 8 waves, 128KB LDS dbuf, 4-phase interleave,
// counted vmcnt (never 0 in steady state), raw s_barrier, setprio, XCD swizzle.
// =============================================================================
template<int EPI>
__global__ __launch_bounds__(512)
void gemm8(const __bf16* __restrict__ A, const __bf16* __restrict__ Bt,
           const float* __restrict__ bias, __bf16* __restrict__ o0,
           __bf16* __restrict__ o1, int M, int N, int K, int klen)
{
    __shared__ __align__(16) char smem[131072];
    const int tid = threadIdx.x;
    const int wid = tid >> 6, lane = tid & 63;
    const int l15 = lane & 15, l16 = lane >> 4;
    const int wm = wid >> 2, wn = wid & 3;

    const int gx = gridDim.x;
    const int nwg = gx * gridDim.y;
    int wg = blockIdx.y * gx + blockIdx.x;
    wg = (wg & 7) * (nwg >> 3) + (wg >> 3);       // nwg % 8 == 0 for all grids
    const int n0 = (wg % gx) * 256;
    const int m0 = (wg / gx) * 256;
    const int kz = blockIdx.z * klen;
    const size_t K2 = (size_t)K * 2;

    const int srow = tid >> 3;
    const int scol = ((tid & 7) * 16) ^ ((srow & 7) << 4);
    const char* gA = (const char*)A + (size_t)(m0 + srow) * K2 + (size_t)kz * 2 + scol;
    const char* gB = (const char*)Bt + (size_t)(n0 + srow) * K2 + (size_t)kz * 2 + scol;

    auto stageA = [&](int c) {
        char* d = (char*)smem + c * 32768 + wid * 1024;
        gload_lds16(d,         gA);
        gload_lds16(d + 8192,  gA + 64 * K2);
        gload_lds16(d + 16384, gA + 128 * K2);
        gload_lds16(d + 24576, gA + 192 * K2);
    };
    auto stageB = [&](int c) {
        char* d = (char*)smem + 65536 + c * 32768 + wid * 1024;
        gload_lds16(d,         gB);
        gload_lds16(d + 8192,  gB + 64 * K2);
        gload_lds16(d + 16384, gB + 128 * K2);
        gload_lds16(d + 24576, gB + 192 * K2);
    };

    const int sw = (l15 & 7) << 4;
    const int x0 = (l16 * 16) ^ sw;
    const int x1 = (64 + l16 * 16) ^ sw;
    const int aoff = (wm * 128 + l15) * 128;
    const int boff = 65536 + (wn * 64 + l15) * 128;

    f32x4 acc[8][4] = {};
    const int NT = klen >> 6;

    stageA(0); stageB(0); gA += 128; gB += 128;
    stageA(1); stageB(1); gA += 128; gB += 128;
    asm volatile("s_waitcnt vmcnt(8)" ::: "memory");
    __builtin_amdgcn_s_barrier();

    for (int t = 0; t < NT; ++t) {
        const int cur = t & 1;
        const char* sa = (const char*)smem + cur * 32768;
        const bool pf = (t + 2) < NT;

        bf16x8 af0[8], af1[8];
        bf16x8 b00, b01, b02, b03, b10, b11, b12, b13;

        // P1: A(kk0) + B(ni0,1 kk0) reads; MFMA ni0,1 kk0
#pragma unroll
        for (int mi = 0; mi < 8; ++mi)
            af0[mi] = *(const bf16x8*)(sa + aoff + mi * 2048 + x0);
        b00 = *(const bf16x8*)(sa + boff + 0 * 2048 + x0);
        b01 = *(const bf16x8*)(sa + boff + 1 * 2048 + x0);
        FENCE();
        __builtin_amdgcn_s_barrier();
        __builtin_amdgcn_s_setprio(1);
#pragma unroll
        for (int mi = 0; mi < 8; ++mi) {
            acc[mi][0] = __builtin_amdgcn_mfma_f32_16x16x32_bf16(af0[mi], b00, acc[mi][0], 0, 0, 0);
            acc[mi][1] = __builtin_amdgcn_mfma_f32_16x16x32_bf16(af0[mi], b01, acc[mi][1], 0, 0, 0);
        }
        __builtin_amdgcn_s_setprio(0);

        // P2: A(kk1) + B(ni2,3 kk0) reads; MFMA ni2,3 kk0
#pragma unroll
        for (int mi = 0; mi < 8; ++mi)
            af1[mi] = *(const bf16x8*)(sa + aoff + mi * 2048 + x1);
        b02 = *(const bf16x8*)(sa + boff + 2 * 2048 + x0);
        b03 = *(const bf16x8*)(sa + boff + 3 * 2048 + x0);
        FENCE();
        __builtin_amdgcn_s_barrier();
        __builtin_amdgcn_s_setprio(1);
#pragma unroll
        for (int mi = 0; mi < 8; ++mi) {
            acc[mi][2] = __builtin_amdgcn_mfma_f32_16x16x32_bf16(af0[mi], b02, acc[mi][2], 0, 0, 0);
            acc[mi][3] = __builtin_amdgcn_mfma_f32_16x16x32_bf16(af0[mi], b03, acc[mi][3], 0, 0, 0);
        }
        __builtin_amdgcn_s_setprio(0);

        // P3: B(ni0,1 kk1) reads; barrier (A region free); prefetch A(t+2); MFMA
        b10 = *(const bf16x8*)(sa + boff + 0 * 2048 + x1);
        b11 = *(const bf16x8*)(sa + boff + 1 * 2048 + x1);
        FENCE();
        __builtin_amdgcn_s_barrier();
        if (pf) stageA(cur);
        __builtin_amdgcn_s_setprio(1);
#pragma unroll
        for (int mi = 0; mi < 8; ++mi) {
            acc[mi][0] = __builtin_amdgcn_mfma_f32_16x16x32_bf16(af1[mi], b10, acc[mi][0], 0, 0, 0);
            acc[mi][1] = __builtin_amdgcn_mfma_f32_16x16x32_bf16(af1[mi], b11, acc[mi][1], 0, 0, 0);
        }
        __builtin_amdgcn_s_setprio(0);

        // P4: B(ni2,3 kk1) reads; barrier (B region free); prefetch B(t+2); MFMA
        b12 = *(const bf16x8*)(sa + boff + 2 * 2048 + x1);
        b13 = *(const bf16x8*)(sa + boff + 3 * 2048 + x1);
        FENCE();
        __builtin_amdgcn_s_barrier();
        if (pf) { stageB(cur); gA += 128; gB += 128; }
        __builtin_amdgcn_s_setprio(1);
#pragma unroll
        for (int mi = 0; mi < 8; ++mi) {
            acc[mi][2] = __builtin_amdgcn_mfma_f32_16x16x32_bf16(af1[mi], b12, acc[mi][2], 0, 0, 0);
            acc[mi][3] = __builtin_amdgcn_mfma_f32_16x16x32_bf16(af1[mi], b13, acc[mi][3], 0, 0, 0);
        }
        __builtin_amdgcn_s_setprio(0);
        if (pf) asm volatile("s_waitcnt vmcnt(8)" ::: "memory");
        else    asm volatile("s_waitcnt vmcnt(0)" ::: "memory");
        __builtin_amdgcn_s_barrier();
        FENCE();
    }

#pragma unroll
    for (int mi = 0; mi < 8; ++mi)
#pragma unroll
        for (int ni = 0; ni < 4; ++ni) {
            int gc = n0 + wn * 64 + ni * 16 + l15;
            float bb = (EPI == 2) ? 0.f : bias[gc];
#pragma unroll
            for (int r = 0; r < 4; ++r) {
                int gr = m0 + wm * 128 + mi * 16 + l16 * 4 + r;
                float v = acc[mi][ni][r] + bb;
                if constexpr (EPI == 0) {
                    o0[(size_t)gr * N + gc] = (__bf16)v;
                } else if constexpr (EPI == 1) {
                    o0[(size_t)gr * N + gc] =
                        (__bf16)(0.5f * v * (1.0f + erff(v * 0.70710678118f)));
                } else {
                    const size_t PSZ = (size_t)M_ * 1024;
                    __bf16* po = (blockIdx.z < 2) ? (o0 + blockIdx.z * PSZ)
                                                  : (o1 + (blockIdx.z - 2) * PSZ);
                    po[(size_t)gr * N + gc] = (__bf16)v;
                }
            }
        }
}

// ------ FFN2 reduce: out = x2 + b2 + sum of 4 bf16 partials -------------------
__global__ __launch_bounds__(256)
void ffn2_red(const __bf16* __restrict__ pA, const __bf16* __restrict__ pB,
              const float* __restrict__ x2, const float* __restrict__ b2,
              float* __restrict__ out)
{
    const size_t PSZ = (size_t)M_ * 1024;
    size_t i = ((size_t)blockIdx.x * 256 + threadIdx.x) * 8;
    bf16x8 a0 = *(const bf16x8*)(pA + i);
    bf16x8 a1 = *(const bf16x8*)(pA + PSZ + i);
    bf16x8 c0 = *(const bf16x8*)(pB + i);
    bf16x8 c1 = *(const bf16x8*)(pB + PSZ + i);
    float4 xa = *(const float4*)(x2 + i);
    float4 xb = *(const float4*)(x2 + i + 4);
    float xs[8] = {xa.x, xa.y, xa.z, xa.w, xb.x, xb.y, xb.z, xb.w};
#pragma unroll
    for (int j = 0; j < 8; ++j) {
        int col = (int)((i + j) & 1023);
        out[i + j] = xs[j] + b2[col]
                   + (float)a0[j] + (float)a1[j] + (float)c0[j] + (float)c1[j];
    }
}

// ---------------- O-proj GEMM (old 128x128 kernel): resid + extra ------------
__global__ __launch_bounds__(256)
void gemm_bt(const __bf16* __restrict__ A, const __bf16* __restrict__ Bt,
             const float* __restrict__ bias, const float* __restrict__ resid,
             const float* __restrict__ extra, float* __restrict__ outF,
             int M, int N, int K)
{
    __shared__ __align__(16) __bf16 As[128 * 64];
    __shared__ __align__(16) __bf16 Bs[128 * 64];
    const int tid = threadIdx.x;
    const int wid = tid >> 6, lane = tid & 63;
    const int m0 = blockIdx.y * 128, n0 = blockIdx.x * 128;
    const int wm = wid >> 1, wn = wid & 1;
    const int l15 = lane & 15, l16 = lane >> 4;

    f32x4 acc[4][4] = {};
    char* asb = (char*)As;
    char* bsb = (char*)Bs;
    const char* ag = (const char*)A;
    const char* bg = (const char*)Bt;
    const int srow = lane >> 3;
    const int scolsw = ((lane & 7) * 16) ^ (srow << 4);

    for (int k0 = 0; k0 < K; k0 += 64) {
        __syncthreads();
#pragma unroll
        for (int i = 0; i < 4; ++i) {
            int j = wid * 4 + i;
            int row = j * 8 + srow;
            gload_lds16(asb + j * 1024,
                        ag + (size_t)(m0 + row) * (K * 2) + k0 * 2 + scolsw);
        }
#pragma unroll
        for (int i = 0; i < 4; ++i) {
            int j = wid * 4 + i;
            int row = j * 8 + srow;
            gload_lds16(bsb + j * 1024,
                        bg + (size_t)(n0 + row) * (K * 2) + k0 * 2 + scolsw);
        }
        __syncthreads();

        bf16x8 af[4][2], bfr[4][2];
#pragma unroll
        for (int mi = 0; mi < 4; ++mi) {
            int row = wm * 64 + mi * 16 + l15;
            int swl = (row & 7) << 4;
#pragma unroll
            for (int kk = 0; kk < 2; ++kk)
                af[mi][kk] = *(const bf16x8*)(asb + row * 128 + ((l16 * 16 + kk * 64) ^ swl));
        }
#pragma unroll
        for (int ni = 0; ni < 4; ++ni) {
            int row = wn * 64 + ni * 16 + l15;
            int swl = (row & 7) << 4;
#pragma unroll
            for (int kk = 0; kk < 2; ++kk)
                bfr[ni][kk] = *(const bf16x8*)(bsb + row * 128 + ((l16 * 16 + kk * 64) ^ swl));
        }
#pragma unroll
        for (int mi = 0; mi < 4; ++mi)
#pragma unroll
            for (int ni = 0; ni < 4; ++ni) {
                acc[mi][ni] = __builtin_amdgcn_mfma_f32_16x16x32_bf16(af[mi][0], bfr[ni][0], acc[mi][ni], 0, 0, 0);
                acc[mi][ni] = __builtin_amdgcn_mfma_f32_16x16x32_bf16(af[mi][1], bfr[ni][1], acc[mi][ni], 0, 0, 0);
            }
    }

#pragma unroll
    for (int mi = 0; mi < 4; ++mi)
#pragma unroll
        for (int ni = 0; ni < 4; ++ni) {
            int gc = n0 + wn * 64 + ni * 16 + l15;
            float bb = bias[gc];
#pragma unroll
            for (int r = 0; r < 4; ++r) {
                int gr = m0 + wm * 64 + mi * 16 + l16 * 4 + r;
                float v = acc[mi][ni][r] + bb;
                size_t idx = (size_t)gr * N + gc;
                int b = gr >> 11;
                outF[idx] = resid[idx] + v + extra[(size_t)b * N + gc];
            }
        }
}

// ---------------- flash attention: Qh/Kh [bh][s][64], Vt [bh][64][s] ---------
__global__ __launch_bounds__(256)
void attn_fwd(const __bf16* __restrict__ Qh, const __bf16* __restrict__ Kh,
              const __bf16* __restrict__ Vt, __bf16* __restrict__ O)
{
    __shared__ __align__(16) char smem[24576];
    char* Kl = smem;
    char* Vl = smem + 8192;
    char* Pl = smem + 16384;
    const int tid = threadIdx.x, wid = tid >> 6, lane = tid & 63;
    const int l15 = lane & 15, l16 = lane >> 4;
    const int bh = blockIdx.y;
    const int q0 = blockIdx.x * 64 + wid * 16;
    const size_t qkbase = (size_t)bh * S_ * HD_;

    bf16x8 qf[2];
    {
        const __bf16* qp = Qh + qkbase + (size_t)(q0 + l15) * HD_ + l16 * 8;
        qf[0] = *(const bf16x8*)qp;
        qf[1] = *(const bf16x8*)(qp + 32);
    }
    float m = -1e30f, sum = 0.f;
    f32x4 o[4] = {};
    const int srow = lane >> 3;
    const int scolsw = ((lane & 7) * 16) ^ (srow << 4);
    const char* kg = (const char*)(Kh + qkbase);
    const char* vg = (const char*)(Vt + (size_t)bh * HD_ * S_);

    for (int kt = 0; kt < S_ / 64; ++kt) {
        int s0 = kt * 64;
        __syncthreads();
#pragma unroll
        for (int c = 0; c < 2; ++c) {
            int j = wid * 2 + c;
            int row = j * 8 + srow;
            gload_lds16(Kl + j * 1024, kg + (size_t)(s0 + row) * 128 + scolsw);
            gload_lds16(Vl + j * 1024, vg + (size_t)row * (S_ * 2) + s0 * 2 + scolsw);
        }
        __syncthreads();

        f32x4 st[4];
#pragma unroll
        for (int t = 0; t < 4; ++t) {
            int row = t * 16 + l15;
            int swl = (row & 7) << 4;
            bf16x8 ak0 = *(const bf16x8*)(Kl + row * 128 + ((l16 * 16) ^ swl));
            bf16x8 ak1 = *(const bf16x8*)(Kl + row * 128 + ((l16 * 16 + 64) ^ swl));
            f32x4 z = {0.f, 0.f, 0.f, 0.f};
            z = __builtin_amdgcn_mfma_f32_16x16x32_bf16(ak0, qf[0], z, 0, 0, 0);
            st[t] = __builtin_amdgcn_mfma_f32_16x16x32_bf16(ak1, qf[1], z, 0, 0, 0);
        }
        float rmax = -1e30f;
#pragma unroll
        for (int t = 0; t < 4; ++t)
#pragma unroll
            for (int r = 0; r < 4; ++r) rmax = fmaxf(rmax, st[t][r]);
        rmax = fmaxf(rmax, __shfl_xor(rmax, 16));
        rmax = fmaxf(rmax, __shfl_xor(rmax, 32));
        float mnew = fmaxf(m, rmax);
        float corr = __expf(m - mnew);
        float rsum = 0.f;
        float p[4][4];
#pragma unroll
        for (int t = 0; t < 4; ++t)
#pragma unroll
            for (int r = 0; r < 4; ++r) { p[t][r] = __expf(st[t][r] - mnew); rsum += p[t][r]; }
        rsum += __shfl_xor(rsum, 16);
        rsum += __shfl_xor(rsum, 32);
        sum = sum * corr + rsum;
        m = mnew;
        {
            char* pw = Pl + wid * 2048 + l15 * 128;
            int swl = (l15 & 7) << 4;
#pragma unroll
            for (int t = 0; t < 4; ++t) {
                bf16x4 pk;
                pk[0] = (__bf16)p[t][0]; pk[1] = (__bf16)p[t][1];
                pk[2] = (__bf16)p[t][2]; pk[3] = (__bf16)p[t][3];
                *(bf16x4*)(pw + ((t * 32 + l16 * 8) ^ swl)) = pk;
            }
        }
        float c0 = __shfl(corr, l16 * 4 + 0);
        float c1 = __shfl(corr, l16 * 4 + 1);
        float c2 = __shfl(corr, l16 * 4 + 2);
        float c3 = __shfl(corr, l16 * 4 + 3);
#pragma unroll
        for (int dg = 0; dg < 4; ++dg) {
            o[dg][0] *= c0; o[dg][1] *= c1; o[dg][2] *= c2; o[dg][3] *= c3;
        }
        {
            const char* pr = Pl + wid * 2048 + l15 * 128;
            int swp = (l15 & 7) << 4;
            bf16x8 ap0 = *(const bf16x8*)(pr + ((l16 * 16) ^ swp));
            bf16x8 ap1 = *(const bf16x8*)(pr + ((l16 * 16 + 64) ^ swp));
#pragma unroll
            for (int dg = 0; dg < 4; ++dg) {
                int row = dg * 16 + l15;
                int swl = (row & 7) << 4;
                bf16x8 bv0 = *(const bf16x8*)(Vl + row * 128 + ((l16 * 16) ^ swl));
                bf16x8 bv1 = *(const bf16x8*)(Vl + row * 128 + ((l16 * 16 + 64) ^ swl));
                o[dg] = __builtin_amdgcn_mfma_f32_16x16x32_bf16(ap0, bv0, o[dg], 0, 0, 0);
                o[dg] = __builtin_amdgcn_mfma_f32_16x16x32_bf16(ap1, bv1, o[dg], 0, 0, 0);
            }
        }
    }
    int b = bh >> 4, hh = bh & 15;
#pragma unroll
    for (int r = 0; r < 4; ++r) {
        float inv = 1.0f / __shfl(sum, l16 * 4 + r);
        int qg = q0 + l16 * 4 + r;
        __bf16* op = O + ((size_t)(b * S_ + qg) * D_) + hh * HD_;
#pragma unroll
        for (int dg = 0; dg < 4; ++dg)
            op[dg * 16 + l15] = (__bf16)(o[dg][r] * inv);
    }
}

// -----------------------------------------------------------------------------
extern "C" void kernel_launch(void* const* d_in, const int* in_sizes, int n_in,
                              void* d_out, int out_size, void* d_ws, size_t ws_size,
                              hipStream_t stream)
{
    (void)in_sizes; (void)n_in; (void)out_size; (void)ws_size;
    const float* x    = (const float*)d_in[0];
    const float* cond = (const float*)d_in[1];
    const float* cosp = (const float*)d_in[2];
    const float* sinp = (const float*)d_in[3];
    const float* Wq = (const float*)d_in[4];  const float* bq = (const float*)d_in[5];
    const float* Wk = (const float*)d_in[6];  const float* bk = (const float*)d_in[7];
    const float* Wv = (const float*)d_in[8];  const float* bv = (const float*)d_in[9];
    const float* Wo = (const float*)d_in[10]; const float* bo = (const float*)d_in[11];
    // d_in[12..15] = Wqc,bqc,Wkc,bkc : dead (softmax over 1 key == 1)
    const float* Wvc = (const float*)d_in[16]; const float* bvc = (const float*)d_in[17];
    const float* Woc = (const float*)d_in[18]; const float* boc = (const float*)d_in[19];
    const float* W1 = (const float*)d_in[20]; const float* b1 = (const float*)d_in[21];
    const float* W2 = (const float*)d_in[22]; const float* b2 = (const float*)d_in[23];
    const float* g1 = (const float*)d_in[24]; const float* be1 = (const float*)d_in[25];
    const float* g3 = (const float*)d_in[28]; const float* be3 = (const float*)d_in[29];

    char* ws = (char*)d_ws;
    const size_t MB = 1ull << 20;
    __bf16* WqkvT = (__bf16*)(ws + 0 * MB);     // [3072][1024]  0-6 MB
    __bf16* WoT   = (__bf16*)(ws + 6 * MB);     // 6-8
    __bf16* W1T   = (__bf16*)(ws + 8 * MB);     // 8-16
    __bf16* W2T   = (__bf16*)(ws + 16 * MB);    // 16-24
    __bf16* xn    = (__bf16*)(ws + 24 * MB);    // 24-32
    __bf16* qkvh  = (__bf16*)(ws + 32 * MB);    // [4096][3072] 32-56
    __bf16* Qh    = (__bf16*)(ws + 56 * MB);    // 56-64
    __bf16* Kh    = (__bf16*)(ws + 64 * MB);    // 64-72
    __bf16* Vt    = (__bf16*)(ws + 72 * MB);    // 72-80
    __bf16* oflat = (__bf16*)(ws + 80 * MB);    // 80-88
    float*  bqkv  = (float*)(ws + 88 * MB);
    float*  vc    = (float*)(ws + 88 * MB + 16384);
    float*  ocp   = (float*)(ws + 88 * MB + 32768);
    float*  x2    = (float*)(ws + 32 * MB);     // reuses qkvh (dead after rope/vtrans)
    __bf16* hbuf  = (__bf16*)(ws + 48 * MB);    // [4096][4096] 48-80 (Q/K/V dead)
    __bf16* pA    = (__bf16*)(ws + 0 * MB);     // FFN2 partials z0,z1 (weights dead)
    __bf16* pB    = (__bf16*)(ws + 80 * MB);    // FFN2 partials z2,z3 (oflat dead)

    // weights -> bf16 transposed ([N][K]); QKV fused into one [3072][1024]
    tcast<<<dim3(32, 32),  256, 0, stream>>>(Wq, WqkvT,                 1024, 1024);
    tcast<<<dim3(32, 32),  256, 0, stream>>>(Wk, WqkvT + 1024 * 1024,   1024, 1024);
    tcast<<<dim3(32, 32),  256, 0, stream>>>(Wv, WqkvT + 2048 * 1024,   1024, 1024);
    tcast<<<dim3(32, 32),  256, 0, stream>>>(Wo, WoT, 1024, 1024);
    tcast<<<dim3(128, 32), 256, 0, stream>>>(W1, W1T, 1024, 4096);
    tcast<<<dim3(32, 128), 256, 0, stream>>>(W2, W2T, 4096, 1024);
    catb<<<12, 256, 0, stream>>>(bq, bk, bv, bqkv);
    // cond path (block 2 collapses to a per-batch bias)
    colgemv<<<dim3(64, 2), 256, 0, stream>>>(cond, Wvc, bvc, vc, 1024, 1024);
    colgemv<<<dim3(64, 2), 256, 0, stream>>>(vc, Woc, boc, ocp, 1024, 1024);
    // LN1
    ln_cast<<<M_, 256, 0, stream>>>(x, g1, be1, xn);
    // fused QKV GEMM -> qkvh bf16 [4096][3072]
    gemm8<0><<<dim3(12, 16, 1), 512, 0, stream>>>(xn, WqkvT, bqkv, qkvh, nullptr,
                                                  M_, 3072, 1024, 1024);
    // RoPE (Q scaled by 1/sqrt(64)) + V head-transpose
    rope2<<<M_, 128, 0, stream>>>(qkvh, cosp, sinp, Qh, 0, 0.125f);
    rope2<<<M_, 128, 0, stream>>>(qkvh, cosp, sinp, Kh, 1024, 1.0f);
    vtrans2<<<dim3(2, 64, 32), 256, 0, stream>>>(qkvh, Vt);
    // attention
    attn_fwd<<<dim3(32, 32), 256, 0, stream>>>(Qh, Kh, Vt, oflat);
    // O-projection + residual + cond broadcast -> x2 (fp32)
    gemm_bt<<<dim3(8, 32), 256, 0, stream>>>(oflat, WoT, bo, x, ocp, x2,
                                             M_, 1024, 1024);
    // LN3 + FFN1 (gelu) -> hbuf bf16
    ln_cast<<<M_, 256, 0, stream>>>(x2, g3, be3, xn);
    gemm8<1><<<dim3(16, 16, 1), 512, 0, stream>>>(xn, W1T, b1, hbuf, nullptr,
                                                  M_, 4096, 1024, 1024);
    // FFN2 split-K=4 -> bf16 partials; reduce fuses resid + bias -> d_out
    gemm8<2><<<dim3(4, 16, 4), 512, 0, stream>>>(hbuf, W2T, nullptr, pA, pB,
                                                 M_, 1024, 4096, 1024);
    ffn2_red<<<2048, 256, 0, stream>>>(pA, pB, x2, b2, (float*)d_out);
}

// Round 4
// 274.313 us; speedup vs baseline: 3.1213x; 1.0460x over previous
//
#include <hip/hip_runtime.h>
#include <cmath>

#define B_  2
#define S_  2048
#define D_  1024
#define H_  16
#define HD_ 64
#define FF_ 4096
#define M_  4096  /* B_*S_ */

typedef __attribute__((ext_vector_type(8))) __bf16 bf16x8;
typedef __attribute__((ext_vector_type(4))) __bf16 bf16x4;
typedef __attribute__((ext_vector_type(4))) float  f32x4;

__device__ __forceinline__ void gload_lds16(void* lds, const void* g) {
    __builtin_amdgcn_global_load_lds(
        (const __attribute__((address_space(1))) unsigned int*)g,
        (__attribute__((address_space(3))) unsigned int*)lds,
        16, 0, 0);
}

#define FENCE() asm volatile("" ::: "memory")

// ---------------- transpose + cast fp32 [K][N] -> bf16 [N][K] ----------------
__global__ __launch_bounds__(256)
void tcast(const float* __restrict__ src, __bf16* __restrict__ dst, int K, int N)
{
    __shared__ float t[32][33];
    int tx = threadIdx.x & 31, ty = threadIdx.x >> 5;
    int k0 = blockIdx.y * 32, n0 = blockIdx.x * 32;
#pragma unroll
    for (int i = 0; i < 4; ++i)
        t[ty + i * 8][tx] = src[(size_t)(k0 + ty + i * 8) * N + n0 + tx];
    __syncthreads();
#pragma unroll
    for (int i = 0; i < 4; ++i)
        dst[(size_t)(n0 + ty + i * 8) * K + k0 + tx] = (__bf16)t[tx][ty + i * 8];
}

// ------ fused QKV weight transpose-cast (1024x1024 each, z picks matrix) -----
__global__ __launch_bounds__(256)
void tcast3(const float* __restrict__ wa, const float* __restrict__ wb,
            const float* __restrict__ wc, __bf16* __restrict__ dstb)
{
    __shared__ float t[32][33];
    const float* src = blockIdx.z == 0 ? wa : (blockIdx.z == 1 ? wb : wc);
    __bf16* dst = dstb + (size_t)blockIdx.z * 1024 * 1024;
    int tx = threadIdx.x & 31, ty = threadIdx.x >> 5;
    int k0 = blockIdx.y * 32, n0 = blockIdx.x * 32;
#pragma unroll
    for (int i = 0; i < 4; ++i)
        t[ty + i * 8][tx] = src[(size_t)(k0 + ty + i * 8) * 1024 + n0 + tx];
    __syncthreads();
#pragma unroll
    for (int i = 0; i < 4; ++i)
        dst[(size_t)(n0 + ty + i * 8) * 1024 + k0 + tx] = (__bf16)t[tx][ty + i * 8];
}

// ---------------- concat 3 bias vectors --------------------------------------
__global__ __launch_bounds__(256)
void catb(const float* __restrict__ a, const float* __restrict__ b,
          const float* __restrict__ c, float* __restrict__ o)
{
    int i = blockIdx.x * 256 + threadIdx.x;
    o[i] = i < 1024 ? a[i] : (i < 2048 ? b[i - 1024] : c[i - 2048]);
}

// ---- latency-optimized fp32 GEMV: out[b][col] = inp[b]·W[:,col] + bias ------
__global__ __launch_bounds__(256)
void colgemv(const float* __restrict__ inp, const float* __restrict__ W,
             const float* __restrict__ bias, float* __restrict__ out, int K, int N)
{
    __shared__ float part[4][16];
    const int b = blockIdx.y;
    const int t = threadIdx.x;
    const int w = t >> 6, lane = t & 63;
    const int colIdx = lane & 15;
    const int col = blockIdx.x * 16 + colIdx;
    const int ks = w * 4 + (lane >> 4);
    const int kpt = K >> 4;
    const float* ip = inp + (size_t)b * K + ks * kpt;
    const float* wp = W + (size_t)ks * kpt * N + col;
    float acc = 0.f;
#pragma unroll 8
    for (int i = 0; i < kpt; ++i)
        acc += ip[i] * wp[(size_t)i * N];
    acc += __shfl_xor(acc, 16);
    acc += __shfl_xor(acc, 32);
    if (lane < 16) part[w][colIdx] = acc;
    __syncthreads();
    if (t < 16) {
        float r = part[0][t] + part[1][t] + part[2][t] + part[3][t]
                + bias[blockIdx.x * 16 + t];
        out[(size_t)b * N + blockIdx.x * 16 + t] = r;
    }
}

// ---------------- LayerNorm row (D=1024) + cast bf16 -------------------------
__global__ __launch_bounds__(256)
void ln_cast(const float* __restrict__ x, const float* __restrict__ g,
             const float* __restrict__ be, __bf16* __restrict__ out)
{
    int row = blockIdx.x, tid = threadIdx.x;
    const float4* xp = (const float4*)(x + (size_t)row * D_);
    float4 v = xp[tid];
    float s  = v.x + v.y + v.z + v.w;
    float s2 = v.x * v.x + v.y * v.y + v.z * v.z + v.w * v.w;
#pragma unroll
    for (int off = 32; off > 0; off >>= 1) {
        s  += __shfl_down(s, off);
        s2 += __shfl_down(s2, off);
    }
    __shared__ float rs[4], rs2[4];
    int wid = tid >> 6, lane = tid & 63;
    if (lane == 0) { rs[wid] = s; rs2[wid] = s2; }
    __syncthreads();
    float tot  = rs[0] + rs[1] + rs[2] + rs[3];
    float tot2 = rs2[0] + rs2[1] + rs2[2] + rs2[3];
    float mean = tot * (1.0f / D_);
    float var  = tot2 * (1.0f / D_) - mean * mean;
    float rstd = rsqrtf(var + 1e-5f);
    float4 gv = ((const float4*)g)[tid];
    float4 bv = ((const float4*)be)[tid];
    bf16x4 ov;
    ov[0] = (__bf16)((v.x - mean) * rstd * gv.x + bv.x);
    ov[1] = (__bf16)((v.y - mean) * rstd * gv.y + bv.y);
    ov[2] = (__bf16)((v.z - mean) * rstd * gv.z + bv.z);
    ov[3] = (__bf16)((v.w - mean) * rstd * gv.w + bv.w);
    ((bf16x4*)(out + (size_t)row * D_))[tid] = ov;
}

// ------- fused RoPE for Q and K from qkv buffer ([row][3072]) ----------------
__global__ __launch_bounds__(128)
void rope_qk(const __bf16* __restrict__ qkv, const float* __restrict__ cosp,
             const float* __restrict__ sinp, __bf16* __restrict__ Qh,
             __bf16* __restrict__ Kh)
{
    int row = blockIdx.x, tid = threadIdx.x;
    int b = row >> 11, s = row & 2047;
    float4 c  = ((const float4*)(cosp + (size_t)s * 512))[tid];
    float4 sn = ((const float4*)(sinp + (size_t)s * 512))[tid];
    int d0 = tid * 4;
    int h1 = d0 >> 6, dd = d0 & 63;
#pragma unroll
    for (int which = 0; which < 2; ++which) {
        const int off = which * 1024;
        const float scale = which ? 1.0f : 0.125f;
        __bf16* out = which ? Kh : Qh;
        bf16x4 a  = *(const bf16x4*)(qkv + (size_t)row * 3072 + off + tid * 4);
        bf16x4 bb = *(const bf16x4*)(qkv + (size_t)row * 3072 + off + 512 + tid * 4);
        float x1a = (float)a[0],  x1b = (float)a[1],  x1c = (float)a[2],  x1d = (float)a[3];
        float x2a = (float)bb[0], x2b = (float)bb[1], x2c = (float)bb[2], x2d = (float)bb[3];
        bf16x4 o1, o2;
        o1[0] = (__bf16)((x1a * c.x - x2a * sn.x) * scale);
        o1[1] = (__bf16)((x1b * c.y - x2b * sn.y) * scale);
        o1[2] = (__bf16)((x1c * c.z - x2c * sn.z) * scale);
        o1[3] = (__bf16)((x1d * c.w - x2d * sn.w) * scale);
        o2[0] = (__bf16)((x1a * sn.x + x2a * c.x) * scale);
        o2[1] = (__bf16)((x1b * sn.y + x2b * c.y) * scale);
        o2[2] = (__bf16)((x1c * sn.z + x2c * c.z) * scale);
        o2[3] = (__bf16)((x1d * sn.w + x2d * c.w) * scale);
        *(bf16x4*)(out + ((size_t)((b * H_ + h1) * S_ + s) * HD_) + dd) = o1;
        *(bf16x4*)(out + ((size_t)((b * H_ + h1 + 8) * S_ + s) * HD_) + dd) = o2;
    }
}

// ------ per-head transpose from qkv buffer: v-slice -> Vt[bh][d][s] ----------
__global__ __launch_bounds__(256)
void vtrans2(const __bf16* __restrict__ qkv, __bf16* __restrict__ Vt)
{
    __shared__ __bf16 t[32][33];
    int tx = threadIdx.x & 31, ty = threadIdx.x >> 5;
    int bh = blockIdx.z;
    int b = bh >> 4, h = bh & 15;
    int s0 = blockIdx.y * 32, d0 = blockIdx.x * 32;
    __bf16* dst = Vt + (size_t)bh * HD_ * S_;
#pragma unroll
    for (int i = 0; i < 4; ++i)
        t[ty + i * 8][tx] = qkv[(size_t)(b * 2048 + s0 + ty + i * 8) * 3072
                                + 2048 + h * 64 + d0 + tx];
    __syncthreads();
#pragma unroll
    for (int i = 0; i < 4; ++i)
        dst[(size_t)(d0 + ty + i * 8) * S_ + s0 + tx] = t[tx][ty + i * 8];
}

// =============================================================================
// gemm8: 256x256 tile, BK=64, 8 waves, 128KB LDS dbuf, 4-phase interleave,
// counted vmcnt (never 0 in steady state), raw s_barrier, setprio, XCD swizzle.
// =============================================================================
template<int EPI>
__global__ __launch_bounds__(512)
void gemm8(const __bf16* __restrict__ A, const __bf16* __restrict__ Bt,
           const float* __restrict__ bias, __bf16* __restrict__ o0,
           __bf16* __restrict__ o1, int M, int N, int K, int klen)
{
    __shared__ __align__(16) char smem[131072];
    const int tid = threadIdx.x;
    const int wid = tid >> 6, lane = tid & 63;
    const int l15 = lane & 15, l16 = lane >> 4;
    const int wm = wid >> 2, wn = wid & 3;

    const int gx = gridDim.x;
    const int nwg = gx * gridDim.y;
    int wg = blockIdx.y * gx + blockIdx.x;
    wg = (wg & 7) * (nwg >> 3) + (wg >> 3);       // nwg % 8 == 0 for all grids
    const int n0 = (wg % gx) * 256;
    const int m0 = (wg / gx) * 256;
    const int kz = blockIdx.z * klen;
    const size_t K2 = (size_t)K * 2;

    const int srow = tid >> 3;
    const int scol = ((tid & 7) * 16) ^ ((srow & 7) << 4);
    const char* gA = (const char*)A + (size_t)(m0 + srow) * K2 + (size_t)kz * 2 + scol;
    const char* gB = (const char*)Bt + (size_t)(n0 + srow) * K2 + (size_t)kz * 2 + scol;

    auto stageA = [&](int c) {
        char* d = (char*)smem + c * 32768 + wid * 1024;
        gload_lds16(d,         gA);
        gload_lds16(d + 8192,  gA + 64 * K2);
        gload_lds16(d + 16384, gA + 128 * K2);
        gload_lds16(d + 24576, gA + 192 * K2);
    };
    auto stageB = [&](int c) {
        char* d = (char*)smem + 65536 + c * 32768 + wid * 1024;
        gload_lds16(d,         gB);
        gload_lds16(d + 8192,  gB + 64 * K2);
        gload_lds16(d + 16384, gB + 128 * K2);
        gload_lds16(d + 24576, gB + 192 * K2);
    };

    const int sw = (l15 & 7) << 4;
    const int x0 = (l16 * 16) ^ sw;
    const int x1 = (64 + l16 * 16) ^ sw;
    const int aoff = (wm * 128 + l15) * 128;
    const int boff = 65536 + (wn * 64 + l15) * 128;

    f32x4 acc[8][4] = {};
    const int NT = klen >> 6;

    stageA(0); stageB(0); gA += 128; gB += 128;
    stageA(1); stageB(1); gA += 128; gB += 128;
    asm volatile("s_waitcnt vmcnt(8)" ::: "memory");
    __builtin_amdgcn_s_barrier();

    for (int t = 0; t < NT; ++t) {
        const int cur = t & 1;
        const char* sa = (const char*)smem + cur * 32768;
        const bool pf = (t + 2) < NT;

        bf16x8 af0[8], af1[8];
        bf16x8 b00, b01, b02, b03, b10, b11, b12, b13;

        // P1: A(kk0) + B(ni0,1 kk0) reads; MFMA ni0,1 kk0
#pragma unroll
        for (int mi = 0; mi < 8; ++mi)
            af0[mi] = *(const bf16x8*)(sa + aoff + mi * 2048 + x0);
        b00 = *(const bf16x8*)(sa + boff + 0 * 2048 + x0);
        b01 = *(const bf16x8*)(sa + boff + 1 * 2048 + x0);
        FENCE();
        __builtin_amdgcn_s_barrier();
        __builtin_amdgcn_s_setprio(1);
#pragma unroll
        for (int mi = 0; mi < 8; ++mi) {
            acc[mi][0] = __builtin_amdgcn_mfma_f32_16x16x32_bf16(af0[mi], b00, acc[mi][0], 0, 0, 0);
            acc[mi][1] = __builtin_amdgcn_mfma_f32_16x16x32_bf16(af0[mi], b01, acc[mi][1], 0, 0, 0);
        }
        __builtin_amdgcn_s_setprio(0);

        // P2: A(kk1) + B(ni2,3 kk0) reads; MFMA ni2,3 kk0
#pragma unroll
        for (int mi = 0; mi < 8; ++mi)
            af1[mi] = *(const bf16x8*)(sa + aoff + mi * 2048 + x1);
        b02 = *(const bf16x8*)(sa + boff + 2 * 2048 + x0);
        b03 = *(const bf16x8*)(sa + boff + 3 * 2048 + x0);
        FENCE();
        __builtin_amdgcn_s_barrier();
        __builtin_amdgcn_s_setprio(1);
#pragma unroll
        for (int mi = 0; mi < 8; ++mi) {
            acc[mi][2] = __builtin_amdgcn_mfma_f32_16x16x32_bf16(af0[mi], b02, acc[mi][2], 0, 0, 0);
            acc[mi][3] = __builtin_amdgcn_mfma_f32_16x16x32_bf16(af0[mi], b03, acc[mi][3], 0, 0, 0);
        }
        __builtin_amdgcn_s_setprio(0);

        // P3: B(ni0,1 kk1) reads; barrier (A region free); prefetch A(t+2); MFMA
        b10 = *(const bf16x8*)(sa + boff + 0 * 2048 + x1);
        b11 = *(const bf16x8*)(sa + boff + 1 * 2048 + x1);
        FENCE();
        __builtin_amdgcn_s_barrier();
        if (pf) stageA(cur);
        __builtin_amdgcn_s_setprio(1);
#pragma unroll
        for (int mi = 0; mi < 8; ++mi) {
            acc[mi][0] = __builtin_amdgcn_mfma_f32_16x16x32_bf16(af1[mi], b10, acc[mi][0], 0, 0, 0);
            acc[mi][1] = __builtin_amdgcn_mfma_f32_16x16x32_bf16(af1[mi], b11, acc[mi][1], 0, 0, 0);
        }
        __builtin_amdgcn_s_setprio(0);

        // P4: B(ni2,3 kk1) reads; barrier (B region free); prefetch B(t+2); MFMA
        b12 = *(const bf16x8*)(sa + boff + 2 * 2048 + x1);
        b13 = *(const bf16x8*)(sa + boff + 3 * 2048 + x1);
        FENCE();
        __builtin_amdgcn_s_barrier();
        if (pf) { stageB(cur); gA += 128; gB += 128; }
        __builtin_amdgcn_s_setprio(1);
#pragma unroll
        for (int mi = 0; mi < 8; ++mi) {
            acc[mi][2] = __builtin_amdgcn_mfma_f32_16x16x32_bf16(af1[mi], b12, acc[mi][2], 0, 0, 0);
            acc[mi][3] = __builtin_amdgcn_mfma_f32_16x16x32_bf16(af1[mi], b13, acc[mi][3], 0, 0, 0);
        }
        __builtin_amdgcn_s_setprio(0);
        if (pf) asm volatile("s_waitcnt vmcnt(8)" ::: "memory");
        else    asm volatile("s_waitcnt vmcnt(0)" ::: "memory");
        __builtin_amdgcn_s_barrier();
        FENCE();
    }

#pragma unroll
    for (int mi = 0; mi < 8; ++mi)
#pragma unroll
        for (int ni = 0; ni < 4; ++ni) {
            int gc = n0 + wn * 64 + ni * 16 + l15;
            float bb = (EPI == 2) ? 0.f : bias[gc];
#pragma unroll
            for (int r = 0; r < 4; ++r) {
                int gr = m0 + wm * 128 + mi * 16 + l16 * 4 + r;
                float v = acc[mi][ni][r] + bb;
                if constexpr (EPI == 0) {
                    o0[(size_t)gr * N + gc] = (__bf16)v;
                } else if constexpr (EPI == 1) {
                    o0[(size_t)gr * N + gc] =
                        (__bf16)(0.5f * v * (1.0f + erff(v * 0.70710678118f)));
                } else {
                    const size_t PSZ = (size_t)M_ * 1024;
                    __bf16* po = (blockIdx.z < 2) ? (o0 + blockIdx.z * PSZ)
                                                  : (o1 + (blockIdx.z - 2) * PSZ);
                    po[(size_t)gr * N + gc] = (__bf16)v;
                }
            }
        }
}

// ------ FFN2 reduce: out = x2 + b2 + sum of 4 bf16 partials -------------------
__global__ __launch_bounds__(256)
void ffn2_red(const __bf16* __restrict__ pA, const __bf16* __restrict__ pB,
              const float* __restrict__ x2, const float* __restrict__ b2,
              float* __restrict__ out)
{
    const size_t PSZ = (size_t)M_ * 1024;
    size_t i = ((size_t)blockIdx.x * 256 + threadIdx.x) * 8;
    bf16x8 a0 = *(const bf16x8*)(pA + i);
    bf16x8 a1 = *(const bf16x8*)(pA + PSZ + i);
    bf16x8 c0 = *(const bf16x8*)(pB + i);
    bf16x8 c1 = *(const bf16x8*)(pB + PSZ + i);
    float4 xa = *(const float4*)(x2 + i);
    float4 xb = *(const float4*)(x2 + i + 4);
    float xs[8] = {xa.x, xa.y, xa.z, xa.w, xb.x, xb.y, xb.z, xb.w};
#pragma unroll
    for (int j = 0; j < 8; ++j) {
        int col = (int)((i + j) & 1023);
        out[i + j] = xs[j] + b2[col]
                   + (float)a0[j] + (float)a1[j] + (float)c0[j] + (float)c1[j];
    }
}

// ---------------- O-proj GEMM (128x128): resid + extra -----------------------
__global__ __launch_bounds__(256)
void gemm_bt(const __bf16* __restrict__ A, const __bf16* __restrict__ Bt,
             const float* __restrict__ bias, const float* __restrict__ resid,
             const float* __restrict__ extra, float* __restrict__ outF,
             int M, int N, int K)
{
    __shared__ __align__(16) __bf16 As[128 * 64];
    __shared__ __align__(16) __bf16 Bs[128 * 64];
    const int tid = threadIdx.x;
    const int wid = tid >> 6, lane = tid & 63;
    const int m0 = blockIdx.y * 128, n0 = blockIdx.x * 128;
    const int wm = wid >> 1, wn = wid & 1;
    const int l15 = lane & 15, l16 = lane >> 4;

    f32x4 acc[4][4] = {};
    char* asb = (char*)As;
    char* bsb = (char*)Bs;
    const char* ag = (const char*)A;
    const char* bg = (const char*)Bt;
    const int srow = lane >> 3;
    const int scolsw = ((lane & 7) * 16) ^ (srow << 4);

    for (int k0 = 0; k0 < K; k0 += 64) {
        __syncthreads();
#pragma unroll
        for (int i = 0; i < 4; ++i) {
            int j = wid * 4 + i;
            int row = j * 8 + srow;
            gload_lds16(asb + j * 1024,
                        ag + (size_t)(m0 + row) * (K * 2) + k0 * 2 + scolsw);
        }
#pragma unroll
        for (int i = 0; i < 4; ++i) {
            int j = wid * 4 + i;
            int row = j * 8 + srow;
            gload_lds16(bsb + j * 1024,
                        bg + (size_t)(n0 + row) * (K * 2) + k0 * 2 + scolsw);
        }
        __syncthreads();

        bf16x8 af[4][2], bfr[4][2];
#pragma unroll
        for (int mi = 0; mi < 4; ++mi) {
            int row = wm * 64 + mi * 16 + l15;
            int swl = (row & 7) << 4;
#pragma unroll
            for (int kk = 0; kk < 2; ++kk)
                af[mi][kk] = *(const bf16x8*)(asb + row * 128 + ((l16 * 16 + kk * 64) ^ swl));
        }
#pragma unroll
        for (int ni = 0; ni < 4; ++ni) {
            int row = wn * 64 + ni * 16 + l15;
            int swl = (row & 7) << 4;
#pragma unroll
            for (int kk = 0; kk < 2; ++kk)
                bfr[ni][kk] = *(const bf16x8*)(bsb + row * 128 + ((l16 * 16 + kk * 64) ^ swl));
        }
#pragma unroll
        for (int mi = 0; mi < 4; ++mi)
#pragma unroll
            for (int ni = 0; ni < 4; ++ni) {
                acc[mi][ni] = __builtin_amdgcn_mfma_f32_16x16x32_bf16(af[mi][0], bfr[ni][0], acc[mi][ni], 0, 0, 0);
                acc[mi][ni] = __builtin_amdgcn_mfma_f32_16x16x32_bf16(af[mi][1], bfr[ni][1], acc[mi][ni], 0, 0, 0);
            }
    }

#pragma unroll
    for (int mi = 0; mi < 4; ++mi)
#pragma unroll
        for (int ni = 0; ni < 4; ++ni) {
            int gc = n0 + wn * 64 + ni * 16 + l15;
            float bb = bias[gc];
#pragma unroll
            for (int r = 0; r < 4; ++r) {
                int gr = m0 + wm * 64 + mi * 16 + l16 * 4 + r;
                float v = acc[mi][ni][r] + bb;
                size_t idx = (size_t)gr * N + gc;
                int b = gr >> 11;
                outF[idx] = resid[idx] + v + extra[(size_t)b * N + gc];
            }
        }
}

// ---------------- flash attention, pipelined K/V dbuf + defer-max ------------
// Qh/Kh [bh][s][64], Vt [bh][64][s]. Grid: 1024 blocks, XCD-locality mapping.
__global__ __launch_bounds__(256)
void attn_fwd(const __bf16* __restrict__ Qh, const __bf16* __restrict__ Kh,
              const __bf16* __restrict__ Vt, __bf16* __restrict__ O)
{
    // LDS: K dbuf 2x8KB @0, V dbuf 2x8KB @16384, P 8KB @32768
    __shared__ __align__(16) char smem[40960];
    const int tid = threadIdx.x, wid = tid >> 6, lane = tid & 63;
    const int l15 = lane & 15, l16 = lane >> 4;

    // XCD-locality: all 32 q-blocks of one bh land on one XCD (id%8 == bh%8)
    const int wg = blockIdx.x;
    const int rr = wg >> 3;
    const int qb = rr & 31;
    const int bh = (wg & 7) + 8 * (rr >> 5);

    const int q0 = qb * 64 + wid * 16;
    const size_t qkbase = (size_t)bh * S_ * HD_;

    bf16x8 qf[2];
    {
        const __bf16* qp = Qh + qkbase + (size_t)(q0 + l15) * HD_ + l16 * 8;
        qf[0] = *(const bf16x8*)qp;
        qf[1] = *(const bf16x8*)(qp + 32);
    }
    float m = -1e30f, sum = 0.f;
    f32x4 o[4] = {};
    const int srow = lane >> 3;
    const int scolsw = ((lane & 7) * 16) ^ (srow << 4);
    const char* kg = (const char*)(Kh + qkbase);
    const char* vg = (const char*)(Vt + (size_t)bh * HD_ * S_);

    auto stage = [&](int c, int t) {
        int s0 = t * 64;
#pragma unroll
        for (int cc = 0; cc < 2; ++cc) {
            int j = wid * 2 + cc;
            int row = j * 8 + srow;
            gload_lds16(smem + c * 8192 + j * 1024,
                        kg + (size_t)(s0 + row) * 128 + scolsw);
            gload_lds16(smem + 16384 + c * 8192 + j * 1024,
                        vg + (size_t)row * (S_ * 2) + s0 * 2 + scolsw);
        }
    };

    const int NT = S_ / 64;
    stage(0, 0);
    stage(1, 1);
    asm volatile("s_waitcnt vmcnt(4)" ::: "memory");   // tile-0 loads landed
    __builtin_amdgcn_s_barrier();

    for (int kt = 0; kt < NT; ++kt) {
        const int cur = kt & 1;
        const char* Kl = smem + cur * 8192;
        const char* Vl = smem + 16384 + cur * 8192;
        char* Pl = smem + 32768;

        // S^T = K · Q^T : st[t] holds score(k = kt*64+t*16+l16*4+r, q = q0+l15)
        f32x4 st[4];
        __builtin_amdgcn_s_setprio(1);
#pragma unroll
        for (int t = 0; t < 4; ++t) {
            int row = t * 16 + l15;
            int swl = (row & 7) << 4;
            bf16x8 ak0 = *(const bf16x8*)(Kl + row * 128 + ((l16 * 16) ^ swl));
            bf16x8 ak1 = *(const bf16x8*)(Kl + row * 128 + ((l16 * 16 + 64) ^ swl));
            f32x4 z = {0.f, 0.f, 0.f, 0.f};
            z = __builtin_amdgcn_mfma_f32_16x16x32_bf16(ak0, qf[0], z, 0, 0, 0);
            st[t] = __builtin_amdgcn_mfma_f32_16x16x32_bf16(ak1, qf[1], z, 0, 0, 0);
        }
        __builtin_amdgcn_s_setprio(0);

        // online softmax with defer-max (THR=8): skip rescale if max not grown
        float rmax = -1e30f;
#pragma unroll
        for (int t = 0; t < 4; ++t)
#pragma unroll
            for (int r = 0; r < 4; ++r) rmax = fmaxf(rmax, st[t][r]);
        rmax = fmaxf(rmax, __shfl_xor(rmax, 16));
        rmax = fmaxf(rmax, __shfl_xor(rmax, 32));
        if (!__all(rmax <= m + 8.f)) {
            float mnew = fmaxf(m, rmax);
            float corr = __expf(m - mnew);
            sum *= corr;
            float c0 = __shfl(corr, l16 * 4 + 0);
            float c1 = __shfl(corr, l16 * 4 + 1);
            float c2 = __shfl(corr, l16 * 4 + 2);
            float c3 = __shfl(corr, l16 * 4 + 3);
#pragma unroll
            for (int dg = 0; dg < 4; ++dg) {
                o[dg][0] *= c0; o[dg][1] *= c1; o[dg][2] *= c2; o[dg][3] *= c3;
            }
            m = mnew;
        }
        float rsum = 0.f;
        float p[4][4];
#pragma unroll
        for (int t = 0; t < 4; ++t)
#pragma unroll
            for (int r = 0; r < 4; ++r) { p[t][r] = __expf(st[t][r] - m); rsum += p[t][r]; }
        rsum += __shfl_xor(rsum, 16);
        rsum += __shfl_xor(rsum, 32);
        sum += rsum;

        // P -> wave-private LDS as P[q=l15][k], swizzled
        {
            char* pw = Pl + wid * 2048 + l15 * 128;
            int swl = (l15 & 7) << 4;
#pragma unroll
            for (int t = 0; t < 4; ++t) {
                bf16x4 pk;
                pk[0] = (__bf16)p[t][0]; pk[1] = (__bf16)p[t][1];
                pk[2] = (__bf16)p[t][2]; pk[3] = (__bf16)p[t][3];
                *(bf16x4*)(pw + ((t * 32 + l16 * 8) ^ swl)) = pk;
            }
        }
        // PV: O[q][d] += P[q][k] · V[k][d]
        {
            const char* pr = Pl + wid * 2048 + l15 * 128;
            int swp = (l15 & 7) << 4;
            bf16x8 ap0 = *(const bf16x8*)(pr + ((l16 * 16) ^ swp));
            bf16x8 ap1 = *(const bf16x8*)(pr + ((l16 * 16 + 64) ^ swp));
            __builtin_amdgcn_s_setprio(1);
#pragma unroll
            for (int dg = 0; dg < 4; ++dg) {
                int row = dg * 16 + l15;
                int swl = (row & 7) << 4;
                bf16x8 bv0 = *(const bf16x8*)(Vl + row * 128 + ((l16 * 16) ^ swl));
                bf16x8 bv1 = *(const bf16x8*)(Vl + row * 128 + ((l16 * 16 + 64) ^ swl));
                o[dg] = __builtin_amdgcn_mfma_f32_16x16x32_bf16(ap0, bv0, o[dg], 0, 0, 0);
                o[dg] = __builtin_amdgcn_mfma_f32_16x16x32_bf16(ap1, bv1, o[dg], 0, 0, 0);
            }
            __builtin_amdgcn_s_setprio(0);
        }

        // pipeline: all waves done reading cur bufs -> refill with tile kt+2
        FENCE();
        __builtin_amdgcn_s_barrier();
        if (kt + 2 < NT) {
            stage(cur, kt + 2);
            asm volatile("s_waitcnt vmcnt(4)" ::: "memory");  // kt+1 landed
        } else {
            asm volatile("s_waitcnt vmcnt(0)" ::: "memory");
        }
        __builtin_amdgcn_s_barrier();
        FENCE();
    }

    int b = bh >> 4, hh = bh & 15;
#pragma unroll
    for (int r = 0; r < 4; ++r) {
        float inv = 1.0f / __shfl(sum, l16 * 4 + r);
        int qg = q0 + l16 * 4 + r;
        __bf16* op = O + ((size_t)(b * S_ + qg) * D_) + hh * HD_;
#pragma unroll
        for (int dg = 0; dg < 4; ++dg)
            op[dg * 16 + l15] = (__bf16)(o[dg][r] * inv);
    }
}

// -----------------------------------------------------------------------------
extern "C" void kernel_launch(void* const* d_in, const int* in_sizes, int n_in,
                              void* d_out, int out_size, void* d_ws, size_t ws_size,
                              hipStream_t stream)
{
    (void)in_sizes; (void)n_in; (void)out_size; (void)ws_size;
    const float* x    = (const float*)d_in[0];
    const float* cond = (const float*)d_in[1];
    const float* cosp = (const float*)d_in[2];
    const float* sinp = (const float*)d_in[3];
    const float* Wq = (const float*)d_in[4];  const float* bq = (const float*)d_in[5];
    const float* Wk = (const float*)d_in[6];  const float* bk = (const float*)d_in[7];
    const float* Wv = (const float*)d_in[8];  const float* bv = (const float*)d_in[9];
    const float* Wo = (const float*)d_in[10]; const float* bo = (const float*)d_in[11];
    // d_in[12..15] = Wqc,bqc,Wkc,bkc : dead (softmax over 1 key == 1)
    const float* Wvc = (const float*)d_in[16]; const float* bvc = (const float*)d_in[17];
    const float* Woc = (const float*)d_in[18]; const float* boc = (const float*)d_in[19];
    const float* W1 = (const float*)d_in[20]; const float* b1 = (const float*)d_in[21];
    const float* W2 = (const float*)d_in[22]; const float* b2 = (const float*)d_in[23];
    const float* g1 = (const float*)d_in[24]; const float* be1 = (const float*)d_in[25];
    const float* g3 = (const float*)d_in[28]; const float* be3 = (const float*)d_in[29];

    char* ws = (char*)d_ws;
    const size_t MB = 1ull << 20;
    __bf16* WqkvT = (__bf16*)(ws + 0 * MB);     // [3072][1024]  0-6 MB
    __bf16* WoT   = (__bf16*)(ws + 6 * MB);     // 6-8
    __bf16* W1T   = (__bf16*)(ws + 8 * MB);     // 8-16
    __bf16* W2T   = (__bf16*)(ws + 16 * MB);    // 16-24
    __bf16* xn    = (__bf16*)(ws + 24 * MB);    // 24-32
    __bf16* qkvh  = (__bf16*)(ws + 32 * MB);    // [4096][3072] 32-56
    __bf16* Qh    = (__bf16*)(ws + 56 * MB);    // 56-64
    __bf16* Kh    = (__bf16*)(ws + 64 * MB);    // 64-72
    __bf16* Vt    = (__bf16*)(ws + 72 * MB);    // 72-80
    __bf16* oflat = (__bf16*)(ws + 80 * MB);    // 80-88
    float*  bqkv  = (float*)(ws + 88 * MB);
    float*  vc    = (float*)(ws + 88 * MB + 16384);
    float*  ocp   = (float*)(ws + 88 * MB + 32768);
    float*  x2    = (float*)(ws + 32 * MB);     // reuses qkvh (dead after rope/vtrans)
    __bf16* hbuf  = (__bf16*)(ws + 48 * MB);    // [4096][4096] 48-80 (Q/K/V dead)
    __bf16* pA    = (__bf16*)(ws + 0 * MB);     // FFN2 partials z0,z1 (weights dead)
    __bf16* pB    = (__bf16*)(ws + 80 * MB);    // FFN2 partials z2,z3 (oflat dead)

    // weights -> bf16 transposed ([N][K]); QKV fused into one [3072][1024]
    tcast3<<<dim3(32, 32, 3), 256, 0, stream>>>(Wq, Wk, Wv, WqkvT);
    tcast<<<dim3(32, 32),  256, 0, stream>>>(Wo, WoT, 1024, 1024);
    tcast<<<dim3(128, 32), 256, 0, stream>>>(W1, W1T, 1024, 4096);
    tcast<<<dim3(32, 128), 256, 0, stream>>>(W2, W2T, 4096, 1024);
    catb<<<12, 256, 0, stream>>>(bq, bk, bv, bqkv);
    // cond path (block 2 collapses to a per-batch bias)
    colgemv<<<dim3(64, 2), 256, 0, stream>>>(cond, Wvc, bvc, vc, 1024, 1024);
    colgemv<<<dim3(64, 2), 256, 0, stream>>>(vc, Woc, boc, ocp, 1024, 1024);
    // LN1
    ln_cast<<<M_, 256, 0, stream>>>(x, g1, be1, xn);
    // fused QKV GEMM -> qkvh bf16 [4096][3072]
    gemm8<0><<<dim3(12, 16, 1), 512, 0, stream>>>(xn, WqkvT, bqkv, qkvh, nullptr,
                                                  M_, 3072, 1024, 1024);
    // RoPE (Q scaled by 1/sqrt(64)) + V head-transpose
    rope_qk<<<M_, 128, 0, stream>>>(qkvh, cosp, sinp, Qh, Kh);
    vtrans2<<<dim3(2, 64, 32), 256, 0, stream>>>(qkvh, Vt);
    // attention (1024 blocks, XCD-locality mapping inside)
    attn_fwd<<<1024, 256, 0, stream>>>(Qh, Kh, Vt, oflat);
    // O-projection + residual + cond broadcast -> x2 (fp32)
    gemm_bt<<<dim3(8, 32), 256, 0, stream>>>(oflat, WoT, bo, x, ocp, x2,
                                             M_, 1024, 1024);
    // LN3 + FFN1 (gelu) -> hbuf bf16
    ln_cast<<<M_, 256, 0, stream>>>(x2, g3, be3, xn);
    gemm8<1><<<dim3(16, 16, 1), 512, 0, stream>>>(xn, W1T, b1, hbuf, nullptr,
                                                  M_, 4096, 1024, 1024);
    // FFN2 split-K=4 -> bf16 partials; reduce fuses resid + bias -> d_out
    gemm8<2><<<dim3(4, 16, 4), 512, 0, stream>>>(hbuf, W2T, nullptr, pA, pB,
                                                 M_, 1024, 4096, 1024);
    ffn2_red<<<2048, 256, 0, stream>>>(pA, pB, x2, b2, (float*)d_out);
}